// Round 2
// baseline (1849.923 us; speedup 1.0000x reference)
//
#include <hip/hip_runtime.h>

namespace {

constexpr int N    = 40000;
constexpr int E    = 640000;
constexpr int DIM  = 128;
constexpr int NG   = 256;
constexpr int OUTC = 16;
constexpr float BN_EPS = 1e-5f;
constexpr int NBLK = N / 64;  // 625

__device__ __forceinline__ void atomAddF(float* p, float v) {
  unsafeAtomicAdd(p, v);  // global_atomic_add_f32 on gfx950
}

// ---------------- CSR build (order-free segments) ----------------

__global__ void hist_kernel(const int* __restrict__ dst, int* __restrict__ deg) {
  int e = blockIdx.x * blockDim.x + threadIdx.x;
  if (e < E) atomicAdd(&deg[dst[e]], 1);
}

// start[i] = wave-prefix + one atomicAdd per wave on a global counter.
__global__ __launch_bounds__(256) void alloc_kernel(const int* __restrict__ deg,
                                                    int* __restrict__ counter,
                                                    int* __restrict__ start,
                                                    int* __restrict__ cursor) {
  const int i    = blockIdx.x * blockDim.x + threadIdx.x;
  const int lane = threadIdx.x & 63;
  int d = (i < N) ? deg[i] : 0;
  int incl = d;
#pragma unroll
  for (int o = 1; o < 64; o <<= 1) {
    int v = __shfl_up(incl, o, 64);
    if (lane >= o) incl += v;
  }
  int base = 0;
  if (lane == 63) base = atomicAdd(counter, incl);  // incl == wave total at lane 63
  base = __shfl(base, 63, 64);
  int s0 = base + incl - d;
  if (i < N) { start[i] = s0; cursor[i] = s0; }
}

__global__ void fill_kernel(const int* __restrict__ src, const int* __restrict__ dst,
                            int* __restrict__ cursor, int* __restrict__ col) {
  int e = blockIdx.x * blockDim.x + threadIdx.x;
  if (e < E) {
    int p = atomicAdd(&cursor[dst[e]], 1);
    col[p] = src[e];
  }
}

// ---------------- fused GIN layer, part 1 ----------------------------------------
// t = x_i + sum_{j in N(i)} x_j  (into swizzled LDS tile, 64 rows x 128 ch)
// h = t @ W1 + b1   -> global h, plus per-channel sum/sumsq atomics for BN.

__global__ __launch_bounds__(256) void gin1_kernel(const float* __restrict__ xin,
                                                   const int* __restrict__ start,
                                                   const int* __restrict__ deg,
                                                   const int* __restrict__ col,
                                                   const float* __restrict__ W1,
                                                   const float* __restrict__ b1,
                                                   float* __restrict__ h,
                                                   float* __restrict__ stats) {
  __shared__ float tile[64 * 128];  // 32 KB, XOR-swizzled on 16B granules
  const int rb  = blockIdx.x;
  const int tid = threadIdx.x;
  const float4* __restrict__ x4 = (const float4*)xin;

  // ---- phase 1: aggregate 8 rows per 32-lane group ----
  {
    const int g = tid >> 5, l = tid & 31;
    for (int i = 0; i < 8; ++i) {
      const int r    = g * 8 + i;
      const int node = rb * 64 + r;
      float4 a = x4[(size_t)node * 32 + l];
      const int b = start[node], n = deg[node];
      int k = 0;
      for (; k + 4 <= n; k += 4) {
        int j0 = col[b + k], j1 = col[b + k + 1], j2 = col[b + k + 2], j3 = col[b + k + 3];
        float4 v0 = x4[(size_t)j0 * 32 + l];
        float4 v1 = x4[(size_t)j1 * 32 + l];
        float4 v2 = x4[(size_t)j2 * 32 + l];
        float4 v3 = x4[(size_t)j3 * 32 + l];
        a.x += v0.x + v1.x + v2.x + v3.x;
        a.y += v0.y + v1.y + v2.y + v3.y;
        a.z += v0.z + v1.z + v2.z + v3.z;
        a.w += v0.w + v1.w + v2.w + v3.w;
      }
      for (; k < n; ++k) {
        int j = col[b + k];
        float4 v = x4[(size_t)j * 32 + l];
        a.x += v.x; a.y += v.y; a.z += v.z; a.w += v.w;
      }
      *(float4*)&tile[r * 128 + ((l ^ (r & 31)) << 2)] = a;
    }
  }
  __syncthreads();

  // ---- phase 2: 64 rows x 32 cols per wave ----
  const int lane = tid & 63;
  const int c0   = __builtin_amdgcn_readfirstlane((tid >> 6) << 5);

  float acc[32];
#pragma unroll
  for (int j = 0; j < 32; ++j) acc[j] = 0.f;

  for (int k = 0; k < DIM; k += 4) {
    const int k4 = k >> 2;
    float4 a4 = *(const float4*)&tile[lane * 128 + (((k4 ^ (lane & 31))) << 2)];
    const float aa[4] = {a4.x, a4.y, a4.z, a4.w};
#pragma unroll
    for (int kk = 0; kk < 4; ++kk) {
      const float* __restrict__ wr = W1 + (size_t)(k + kk) * DIM + c0;
#pragma unroll
      for (int j = 0; j < 32; ++j) acc[j] = fmaf(aa[kk], wr[j], acc[j]);
    }
  }

  // ---- epilogue: bias, write h, BN stats ----
#pragma unroll
  for (int j = 0; j < 32; ++j) acc[j] += b1[c0 + j];

  float* __restrict__ orow = h + (size_t)(rb * 64 + lane) * DIM + c0;
#pragma unroll
  for (int j = 0; j < 32; j += 4) {
    float4 v = {acc[j], acc[j + 1], acc[j + 2], acc[j + 3]};
    *(float4*)(orow + j) = v;
  }

#pragma unroll
  for (int j = 0; j < 32; ++j) {
    float s = acc[j];
    float q = s * s;
#pragma unroll
    for (int o = 16; o; o >>= 1) {  // reduce within each 32-lane half
      s += __shfl_xor(s, o);
      q += __shfl_xor(q, o);
    }
    if ((lane & 31) == 0) {
      atomAddF(&stats[c0 + j], s);
      atomAddF(&stats[DIM + c0 + j], q);
    }
  }
}

// ---------------- fused GIN layer, part 2 ----------------------------------------
// A = relu(BN(h)) staged coalesced into swizzled LDS; out = relu(A @ W2 + b2).
// BN scale/shift computed per-thread from raw sums (finalize fused).

__global__ __launch_bounds__(256) void gin2_kernel(const float* __restrict__ h,
                                                   const float* __restrict__ stats,
                                                   const float* __restrict__ gamma,
                                                   const float* __restrict__ beta,
                                                   const float* __restrict__ W2,
                                                   const float* __restrict__ b2,
                                                   float* __restrict__ out) {
  __shared__ float tile[64 * 128];
  const int rb  = blockIdx.x;
  const int tid = threadIdx.x;
  const int c4  = tid & 31;  // this thread's float4 channel group (fixed)

  // BN finalize for channels c4*4 .. c4*4+3
  float4 sc, sh;
  {
    const float4 s4 = *(const float4*)&stats[c4 * 4];
    const float4 q4 = *(const float4*)&stats[DIM + c4 * 4];
    const float4 g4 = *(const float4*)&gamma[c4 * 4];
    const float4 b4 = *(const float4*)&beta[c4 * 4];
    const float inv_n = 1.0f / N;
    float mu, var;
    mu = s4.x * inv_n; var = q4.x * inv_n - mu * mu;
    sc.x = g4.x * rsqrtf(var + BN_EPS); sh.x = b4.x - mu * sc.x;
    mu = s4.y * inv_n; var = q4.y * inv_n - mu * mu;
    sc.y = g4.y * rsqrtf(var + BN_EPS); sh.y = b4.y - mu * sc.y;
    mu = s4.z * inv_n; var = q4.z * inv_n - mu * mu;
    sc.z = g4.z * rsqrtf(var + BN_EPS); sh.z = b4.z - mu * sc.z;
    mu = s4.w * inv_n; var = q4.w * inv_n - mu * mu;
    sc.w = g4.w * rsqrtf(var + BN_EPS); sh.w = b4.w - mu * sc.w;
  }

  // ---- phase 1: coalesced stage of 64 rows with BN+relu applied ----
  {
    const float4* __restrict__ h4 = (const float4*)h;
    const int rg = tid >> 5;
    for (int i = 0; i < 8; ++i) {
      const int r = rg + 8 * i;
      float4 v = h4[(size_t)(rb * 64 + r) * 32 + c4];
      v.x = fmaxf(fmaf(v.x, sc.x, sh.x), 0.f);
      v.y = fmaxf(fmaf(v.y, sc.y, sh.y), 0.f);
      v.z = fmaxf(fmaf(v.z, sc.z, sh.z), 0.f);
      v.w = fmaxf(fmaf(v.w, sc.w, sh.w), 0.f);
      *(float4*)&tile[r * 128 + ((c4 ^ (r & 31)) << 2)] = v;
    }
  }
  __syncthreads();

  // ---- phase 2 ----
  const int lane = tid & 63;
  const int c0   = __builtin_amdgcn_readfirstlane((tid >> 6) << 5);

  float acc[32];
#pragma unroll
  for (int j = 0; j < 32; ++j) acc[j] = 0.f;

  for (int k = 0; k < DIM; k += 4) {
    const int k4 = k >> 2;
    float4 a4 = *(const float4*)&tile[lane * 128 + (((k4 ^ (lane & 31))) << 2)];
    const float aa[4] = {a4.x, a4.y, a4.z, a4.w};
#pragma unroll
    for (int kk = 0; kk < 4; ++kk) {
      const float* __restrict__ wr = W2 + (size_t)(k + kk) * DIM + c0;
#pragma unroll
      for (int j = 0; j < 32; ++j) acc[j] = fmaf(aa[kk], wr[j], acc[j]);
    }
  }

  float* __restrict__ orow = out + (size_t)(rb * 64 + lane) * DIM + c0;
#pragma unroll
  for (int j = 0; j < 32; j += 4) {
    float4 v;
    v.x = fmaxf(acc[j + 0] + b2[c0 + j + 0], 0.f);
    v.y = fmaxf(acc[j + 1] + b2[c0 + j + 1], 0.f);
    v.z = fmaxf(acc[j + 2] + b2[c0 + j + 2], 0.f);
    v.w = fmaxf(acc[j + 3] + b2[c0 + j + 3], 0.f);
    *(float4*)(orow + j) = v;
  }
}

// ---------------- segment pooling over sorted batch -------------------------------

__global__ __launch_bounds__(256) void pool_kernel(const float* __restrict__ x1,
                                                   const int* __restrict__ batch,
                                                   float* __restrict__ pooled) {
  const int grp  = (blockIdx.x * blockDim.x + threadIdx.x) >> 5;
  const int lane = threadIdx.x & 31;
  const int node0 = grp * 64;
  if (node0 >= N) return;
  const int end = (node0 + 64 < N) ? (node0 + 64) : N;
  float4 acc = {0, 0, 0, 0};
  int cur = batch[node0];
  for (int n = node0; n < end; ++n) {
    int b = batch[n];
    if (b != cur) {
      atomAddF(&pooled[(size_t)cur * DIM + lane * 4 + 0], acc.x);
      atomAddF(&pooled[(size_t)cur * DIM + lane * 4 + 1], acc.y);
      atomAddF(&pooled[(size_t)cur * DIM + lane * 4 + 2], acc.z);
      atomAddF(&pooled[(size_t)cur * DIM + lane * 4 + 3], acc.w);
      acc = {0, 0, 0, 0};
      cur = b;
    }
    float4 v = ((const float4*)x1)[(size_t)n * 32 + lane];
    acc.x += v.x; acc.y += v.y; acc.z += v.z; acc.w += v.w;
  }
  atomAddF(&pooled[(size_t)cur * DIM + lane * 4 + 0], acc.x);
  atomAddF(&pooled[(size_t)cur * DIM + lane * 4 + 1], acc.y);
  atomAddF(&pooled[(size_t)cur * DIM + lane * 4 + 2], acc.z);
  atomAddF(&pooled[(size_t)cur * DIM + lane * 4 + 3], acc.w);
}

// ---------------- final MLP + log_softmax -----------------------------------------

__global__ __launch_bounds__(128) void mlp_kernel(const float* __restrict__ pooled,
                                                  const float* __restrict__ W1,
                                                  const float* __restrict__ b1,
                                                  const float* __restrict__ W2,
                                                  const float* __restrict__ b2,
                                                  float* __restrict__ out) {
  const int gidx = blockIdx.x;
  const int t    = threadIdx.x;
  __shared__ float p[DIM], a1[DIM];
  p[t] = pooled[(size_t)gidx * DIM + t];
  __syncthreads();
  float acc = b1[t];
  for (int k = 0; k < DIM; ++k) acc = fmaf(p[k], W1[(size_t)k * DIM + t], acc);
  a1[t] = fmaxf(acc, 0.f);
  __syncthreads();
  if (t < OUTC) {
    float o = b2[t];
    for (int k = 0; k < DIM; ++k) o = fmaf(a1[k], W2[(size_t)k * OUTC + t], o);
    float m = o;
    for (int s = 8; s >= 1; s >>= 1) m = fmaxf(m, __shfl_xor(m, s, 16));
    float e = __expf(o - m);
    float se = e;
    for (int s = 8; s >= 1; s >>= 1) se += __shfl_xor(se, s, 16);
    out[(size_t)gidx * OUTC + t] = o - m - __logf(se);
  }
}

}  // namespace

extern "C" void kernel_launch(void* const* d_in, const int* in_sizes, int n_in,
                              void* d_out, int out_size, void* d_ws, size_t ws_size,
                              hipStream_t stream) {
  const float* x     = (const float*)d_in[0];
  const int*   ei    = (const int*)d_in[1];   // [2,E]: src then dst
  const int*   batch = (const int*)d_in[2];
  const float* W1_0  = (const float*)d_in[4];
  const float* b1_0  = (const float*)d_in[5];
  const float* g_0   = (const float*)d_in[6];
  const float* bt_0  = (const float*)d_in[7];
  const float* W2_0  = (const float*)d_in[8];
  const float* b2_0  = (const float*)d_in[9];
  const float* W1s   = (const float*)d_in[10];
  const float* b1s   = (const float*)d_in[11];
  const float* gs    = (const float*)d_in[12];
  const float* bts   = (const float*)d_in[13];
  const float* W2s   = (const float*)d_in[14];
  const float* b2s   = (const float*)d_in[15];
  const float* lin1W = (const float*)d_in[16];
  const float* lin1b = (const float*)d_in[17];
  const float* lin2W = (const float*)d_in[18];
  const float* lin2b = (const float*)d_in[19];

  float* out_ls = (float*)d_out;                 // [256,16]
  float* x1_out = (float*)d_out + NG * OUTC;     // [40000,128] — single layer-out buffer

  // workspace carve (256B aligned)
  char* w = (char*)d_ws;
  auto alloc = [&](size_t bytes) -> void* {
    void* p = (void*)w;
    w += (bytes + 255) & ~(size_t)255;
    return p;
  };
  int*   deg      = (int*)alloc((size_t)(N + 64) * 4);  // deg[N] + counter (contiguous zero region)
  int*   counter  = deg + N;
  int*   start    = (int*)alloc((size_t)N * 4);
  int*   cursor   = (int*)alloc((size_t)N * 4);
  int*   col      = (int*)alloc((size_t)E * 4);
  float* bufA     = (float*)alloc((size_t)N * DIM * 4);
  float* statsAll = (float*)alloc((size_t)(5 * 2 * DIM + NG * DIM) * 4);  // stats + pooled contiguous
  float* pooled   = statsAll + 5 * 2 * DIM;

  const int* src = ei;
  const int* dst = ei + E;

  // ---- zero deg+counter and stats+pooled (single memsets) ----
  hipMemsetAsync(deg, 0, (size_t)(N + 64) * 4, stream);
  hipMemsetAsync(statsAll, 0, (size_t)(5 * 2 * DIM + NG * DIM) * 4, stream);

  // ---- CSR build (order-free) ----
  hist_kernel<<<E / 256, 256, 0, stream>>>(dst, deg);
  alloc_kernel<<<(N + 255) / 256, 256, 0, stream>>>(deg, counter, start, cursor);
  fill_kernel<<<E / 256, 256, 0, stream>>>(src, dst, cursor, col);

  // ---- 5 GIN layers: gin1 (agg+W1+stats) -> gin2 (BN+relu+W2+relu) ----
  const float* xin = x;
  for (int l = 0; l < 5; ++l) {
    const float* W1 = (l == 0) ? W1_0 : W1s + (size_t)(l - 1) * DIM * DIM;
    const float* b1 = (l == 0) ? b1_0 : b1s + (size_t)(l - 1) * DIM;
    const float* gg = (l == 0) ? g_0  : gs  + (size_t)(l - 1) * DIM;
    const float* bb = (l == 0) ? bt_0 : bts + (size_t)(l - 1) * DIM;
    const float* W2 = (l == 0) ? W2_0 : W2s + (size_t)(l - 1) * DIM * DIM;
    const float* b2 = (l == 0) ? b2_0 : b2s + (size_t)(l - 1) * DIM;
    float* stats = statsAll + (size_t)l * 2 * DIM;

    gin1_kernel<<<NBLK, 256, 0, stream>>>(xin, start, deg, col, W1, b1, bufA, stats);
    gin2_kernel<<<NBLK, 256, 0, stream>>>(bufA, stats, gg, bb, W2, b2, x1_out);
    xin = x1_out;
  }

  // ---- pooling + MLP head ----
  {
    int groups = (N + 63) / 64;                 // 625
    int blocks = (groups * 32 + 255) / 256;     // 79
    pool_kernel<<<blocks, 256, 0, stream>>>(x1_out, batch, pooled);
  }
  mlp_kernel<<<NG, 128, 0, stream>>>(pooled, lin1W, lin1b, lin2W, lin2b, out_ls);
}

// Round 3
// 534.779 us; speedup vs baseline: 3.4592x; 3.4592x over previous
//
#include <hip/hip_runtime.h>

namespace {

constexpr int N    = 40000;
constexpr int E    = 640000;
constexpr int DIM  = 128;
constexpr int NG   = 256;
constexpr int OUTC = 16;
constexpr float BN_EPS = 1e-5f;

typedef __attribute__((ext_vector_type(8))) short bf16x8;
typedef __attribute__((ext_vector_type(4))) float f32x4;

__device__ __forceinline__ void atomAddF(float* p, float v) {
  unsafeAtomicAdd(p, v);
}

// round-to-nearest-even f32 -> bf16 (as uint in low 16)
__device__ __forceinline__ unsigned b16r(float f) {
  unsigned u = __float_as_uint(f);
  return (u + 0x7fffu + ((u >> 16) & 1u)) >> 16;
}
__device__ __forceinline__ unsigned pack2(float a, float b) {
  return b16r(a) | (b16r(b) << 16);
}
__device__ __forceinline__ void add8(float* a, const uint4 v) {
  a[0] += __uint_as_float(v.x << 16);
  a[1] += __uint_as_float(v.x & 0xffff0000u);
  a[2] += __uint_as_float(v.y << 16);
  a[3] += __uint_as_float(v.y & 0xffff0000u);
  a[4] += __uint_as_float(v.z << 16);
  a[5] += __uint_as_float(v.z & 0xffff0000u);
  a[6] += __uint_as_float(v.w << 16);
  a[7] += __uint_as_float(v.w & 0xffff0000u);
}

// ---------------- converts ----------------

__global__ __launch_bounds__(256) void cvt_f32_bf16(const float* __restrict__ in,
                                                    ushort* __restrict__ out) {
  const int i = blockIdx.x * 256 + threadIdx.x;  // uint4 granule = 8 values
  const float4* __restrict__ in4 = (const float4*)in;
  float4 v0 = in4[(size_t)i * 2], v1 = in4[(size_t)i * 2 + 1];
  uint4 o = {pack2(v0.x, v0.y), pack2(v0.z, v0.w), pack2(v1.x, v1.y), pack2(v1.z, v1.w)};
  ((uint4*)out)[i] = o;
}

// W[k][c] f32 -> Wt[m][c][k] bf16   (10 matrices of 128x128)
__global__ __launch_bounds__(64) void transpose_weights(const float* __restrict__ W1_0,
                                                        const float* __restrict__ W2_0,
                                                        const float* __restrict__ W1s,
                                                        const float* __restrict__ W2s,
                                                        ushort* __restrict__ Wt) {
  const int m    = blockIdx.x >> 7;   // 0..9
  const int c    = blockIdx.x & 127;
  const int lane = threadIdx.x;       // 0..63
  const int l    = m >> 1;
  const float* W;
  if (l == 0) W = (m & 1) ? W2_0 : W1_0;
  else        W = ((m & 1) ? W2s : W1s) + (size_t)(l - 1) * DIM * DIM;
  const int k = lane * 2;
  float f0 = W[(size_t)k * DIM + c];
  float f1 = W[(size_t)(k + 1) * DIM + c];
  ((unsigned*)Wt)[((size_t)m * DIM + c) * 64 + lane] = pack2(f0, f1);
}

// ---------------- CSR build (order-free segments) ----------------

__global__ void hist_kernel(const int* __restrict__ dst, int* __restrict__ deg) {
  int e = blockIdx.x * blockDim.x + threadIdx.x;
  if (e < E) atomicAdd(&deg[dst[e]], 1);
}

__global__ __launch_bounds__(256) void alloc_kernel(const int* __restrict__ deg,
                                                    int* __restrict__ counter,
                                                    int* __restrict__ start,
                                                    int* __restrict__ cursor) {
  const int i    = blockIdx.x * blockDim.x + threadIdx.x;
  const int lane = threadIdx.x & 63;
  int d = (i < N) ? deg[i] : 0;
  int incl = d;
#pragma unroll
  for (int o = 1; o < 64; o <<= 1) {
    int v = __shfl_up(incl, o, 64);
    if (lane >= o) incl += v;
  }
  int base = 0;
  if (lane == 63) base = atomicAdd(counter, incl);
  base = __shfl(base, 63, 64);
  int s0 = base + incl - d;
  if (i < N) { start[i] = s0; cursor[i] = s0; }
}

__global__ void fill_kernel(const int* __restrict__ src, const int* __restrict__ dst,
                            int* __restrict__ cursor, int* __restrict__ col) {
  int e = blockIdx.x * blockDim.x + threadIdx.x;
  if (e < E) {
    int p = atomicAdd(&cursor[dst[e]], 1);
    col[p] = src[e];
  }
}

// ---------------- aggregation: t = x_i + sum_j x_j  (bf16 in/out, f32 acc) --------
// 16 lanes per node, 16 B per lane. High TLP: 640k threads.

__global__ __launch_bounds__(256) void aggregate_kernel(const ushort* __restrict__ xb,
                                                        const int* __restrict__ start,
                                                        const int* __restrict__ deg,
                                                        const int* __restrict__ col,
                                                        ushort* __restrict__ t) {
  const int gid  = blockIdx.x * 256 + threadIdx.x;
  const int node = gid >> 4;
  const int l    = threadIdx.x & 15;
  if (node >= N) return;
  const uint4* __restrict__ x16 = (const uint4*)xb;
  float a[8] = {0, 0, 0, 0, 0, 0, 0, 0};
  add8(a, x16[(size_t)node * 16 + l]);
  const int b = start[node], n = deg[node];
  int k = 0;
  for (; k + 4 <= n; k += 4) {
    int j0 = col[b + k], j1 = col[b + k + 1], j2 = col[b + k + 2], j3 = col[b + k + 3];
    uint4 v0 = x16[(size_t)j0 * 16 + l];
    uint4 v1 = x16[(size_t)j1 * 16 + l];
    uint4 v2 = x16[(size_t)j2 * 16 + l];
    uint4 v3 = x16[(size_t)j3 * 16 + l];
    add8(a, v0); add8(a, v1); add8(a, v2); add8(a, v3);
  }
  for (; k < n; ++k) add8(a, x16[(size_t)col[b + k] * 16 + l]);
  uint4 o = {pack2(a[0], a[1]), pack2(a[2], a[3]), pack2(a[4], a[5]), pack2(a[6], a[7])};
  ((uint4*)t)[(size_t)node * 16 + l] = o;
}

// ---------------- MFMA GEMM: out[N,128] = A[N,128] @ W  (+bias, opt relu/stats) ---
// Block: 256 thr = 4 waves; block tile 32 rows; wave tile 32 rows x 32 cols.
// A-frag: row = lane&15, k = 8*(lane>>4)+j (16B contiguous loads from global).
// B-frag from Wt[c][k] (pre-transposed): same layout. D: col=lane&15, row=4*(lane>>4)+reg.

template <int STATS, int RELU, int F32OUT>
__global__ __launch_bounds__(256) void mfma_gemm(const ushort* __restrict__ A,
                                                 const ushort* __restrict__ Wt,
                                                 const float* __restrict__ bias,
                                                 float* __restrict__ stats,
                                                 ushort* __restrict__ outb,
                                                 float* __restrict__ outf) {
  const int tid  = threadIdx.x;
  const int lane = tid & 63;
  const int c0   = (tid >> 6) * 32;
  const int lr   = lane & 15;
  const int lg   = lane >> 4;  // 0..3
  const int row0 = blockIdx.x * 32;

  f32x4 acc00 = {0, 0, 0, 0}, acc01 = {0, 0, 0, 0}, acc10 = {0, 0, 0, 0}, acc11 = {0, 0, 0, 0};

  const ushort* __restrict__ arow = A + (size_t)(row0 + lr) * DIM + lg * 8;
  const ushort* __restrict__ brow = Wt + (size_t)(c0 + lr) * DIM + lg * 8;

#pragma unroll
  for (int ks = 0; ks < 4; ++ks) {
    bf16x8 a0 = *(const bf16x8*)(arow + ks * 32);
    bf16x8 a1 = *(const bf16x8*)(arow + 16 * DIM + ks * 32);
    bf16x8 b0 = *(const bf16x8*)(brow + ks * 32);
    bf16x8 b1 = *(const bf16x8*)(brow + 16 * DIM + ks * 32);
    acc00 = __builtin_amdgcn_mfma_f32_16x16x32_bf16(a0, b0, acc00, 0, 0, 0);
    acc01 = __builtin_amdgcn_mfma_f32_16x16x32_bf16(a0, b1, acc01, 0, 0, 0);
    acc10 = __builtin_amdgcn_mfma_f32_16x16x32_bf16(a1, b0, acc10, 0, 0, 0);
    acc11 = __builtin_amdgcn_mfma_f32_16x16x32_bf16(a1, b1, acc11, 0, 0, 0);
  }

  __syncthreads();  // all A reads complete block-wide -> in-place output is safe

  const float bia0 = bias[c0 + lr];
  const float bia1 = bias[c0 + 16 + lr];
  float s[2] = {0, 0}, q[2] = {0, 0};

  f32x4 accs[2][2] = {{acc00, acc01}, {acc10, acc11}};
#pragma unroll
  for (int rf = 0; rf < 2; ++rf) {
#pragma unroll
    for (int cf = 0; cf < 2; ++cf) {
      const int colidx = c0 + cf * 16 + lr;
      const float bb = cf ? bia1 : bia0;
#pragma unroll
      for (int rg = 0; rg < 4; ++rg) {
        float v = accs[rf][cf][rg] + bb;
        if (RELU) v = fmaxf(v, 0.f);
        const int row = row0 + rf * 16 + lg * 4 + rg;
        if (F32OUT) outf[(size_t)row * DIM + colidx] = v;
        else        outb[(size_t)row * DIM + colidx] = (ushort)b16r(v);
        if (STATS) { s[cf] += v; q[cf] = fmaf(v, v, q[cf]); }
      }
    }
  }

  if (STATS) {
#pragma unroll
    for (int cf = 0; cf < 2; ++cf) {
      float ss = s[cf], qq = q[cf];
      ss += __shfl_xor(ss, 16); ss += __shfl_xor(ss, 32);
      qq += __shfl_xor(qq, 16); qq += __shfl_xor(qq, 32);
      if (lg == 0) {
        atomAddF(&stats[c0 + cf * 16 + lr], ss);
        atomAddF(&stats[DIM + c0 + cf * 16 + lr], qq);
      }
    }
  }
}

// ---------------- BN finalize+apply+relu, in place on bf16 h ----------------------

__global__ __launch_bounds__(256) void bn_apply(ushort* __restrict__ h,
                                                const float* __restrict__ stats,
                                                const float* __restrict__ gamma,
                                                const float* __restrict__ beta) {
  const int tid = blockIdx.x * 256 + threadIdx.x;
  const int cg  = tid & 31;        // 4-channel group
  const int r0  = (tid >> 5) * 8;  // 8 rows per thread
  const float4 s4 = *(const float4*)&stats[cg * 4];
  const float4 q4 = *(const float4*)&stats[DIM + cg * 4];
  const float4 g4 = *(const float4*)&gamma[cg * 4];
  const float4 b4 = *(const float4*)&beta[cg * 4];
  const float inv_n = 1.0f / N;
  float sc[4], sh[4];
  {
    float mu, var;
    mu = s4.x * inv_n; var = q4.x * inv_n - mu * mu;
    sc[0] = g4.x * rsqrtf(var + BN_EPS); sh[0] = b4.x - mu * sc[0];
    mu = s4.y * inv_n; var = q4.y * inv_n - mu * mu;
    sc[1] = g4.y * rsqrtf(var + BN_EPS); sh[1] = b4.y - mu * sc[1];
    mu = s4.z * inv_n; var = q4.z * inv_n - mu * mu;
    sc[2] = g4.z * rsqrtf(var + BN_EPS); sh[2] = b4.z - mu * sc[2];
    mu = s4.w * inv_n; var = q4.w * inv_n - mu * mu;
    sc[3] = g4.w * rsqrtf(var + BN_EPS); sh[3] = b4.w - mu * sc[3];
  }
  uint2* __restrict__ h2 = (uint2*)h;
  for (int r = r0; r < r0 + 8; ++r) {
    uint2 v = h2[(size_t)r * 32 + cg];
    float f0 = __uint_as_float(v.x << 16);
    float f1 = __uint_as_float(v.x & 0xffff0000u);
    float f2 = __uint_as_float(v.y << 16);
    float f3 = __uint_as_float(v.y & 0xffff0000u);
    f0 = fmaxf(fmaf(f0, sc[0], sh[0]), 0.f);
    f1 = fmaxf(fmaf(f1, sc[1], sh[1]), 0.f);
    f2 = fmaxf(fmaf(f2, sc[2], sh[2]), 0.f);
    f3 = fmaxf(fmaf(f3, sc[3], sh[3]), 0.f);
    v.x = pack2(f0, f1);
    v.y = pack2(f2, f3);
    h2[(size_t)r * 32 + cg] = v;
  }
}

// ---------------- segment pooling over sorted batch -------------------------------

__global__ __launch_bounds__(256) void pool_kernel(const float* __restrict__ x1,
                                                   const int* __restrict__ batch,
                                                   float* __restrict__ pooled) {
  const int grp  = (blockIdx.x * blockDim.x + threadIdx.x) >> 5;
  const int lane = threadIdx.x & 31;
  const int node0 = grp * 64;
  if (node0 >= N) return;
  const int end = (node0 + 64 < N) ? (node0 + 64) : N;
  float4 acc = {0, 0, 0, 0};
  int cur = batch[node0];
  for (int n = node0; n < end; ++n) {
    int b = batch[n];
    if (b != cur) {
      atomAddF(&pooled[(size_t)cur * DIM + lane * 4 + 0], acc.x);
      atomAddF(&pooled[(size_t)cur * DIM + lane * 4 + 1], acc.y);
      atomAddF(&pooled[(size_t)cur * DIM + lane * 4 + 2], acc.z);
      atomAddF(&pooled[(size_t)cur * DIM + lane * 4 + 3], acc.w);
      acc = {0, 0, 0, 0};
      cur = b;
    }
    float4 v = ((const float4*)x1)[(size_t)n * 32 + lane];
    acc.x += v.x; acc.y += v.y; acc.z += v.z; acc.w += v.w;
  }
  atomAddF(&pooled[(size_t)cur * DIM + lane * 4 + 0], acc.x);
  atomAddF(&pooled[(size_t)cur * DIM + lane * 4 + 1], acc.y);
  atomAddF(&pooled[(size_t)cur * DIM + lane * 4 + 2], acc.z);
  atomAddF(&pooled[(size_t)cur * DIM + lane * 4 + 3], acc.w);
}

// ---------------- final MLP + log_softmax -----------------------------------------

__global__ __launch_bounds__(128) void mlp_kernel(const float* __restrict__ pooled,
                                                  const float* __restrict__ W1,
                                                  const float* __restrict__ b1,
                                                  const float* __restrict__ W2,
                                                  const float* __restrict__ b2,
                                                  float* __restrict__ out) {
  const int gidx = blockIdx.x;
  const int t    = threadIdx.x;
  __shared__ float p[DIM], a1[DIM];
  p[t] = pooled[(size_t)gidx * DIM + t];
  __syncthreads();
  float acc = b1[t];
  for (int k = 0; k < DIM; ++k) acc = fmaf(p[k], W1[(size_t)k * DIM + t], acc);
  a1[t] = fmaxf(acc, 0.f);
  __syncthreads();
  if (t < OUTC) {
    float o = b2[t];
    for (int k = 0; k < DIM; ++k) o = fmaf(a1[k], W2[(size_t)k * OUTC + t], o);
    float m = o;
    for (int s = 8; s >= 1; s >>= 1) m = fmaxf(m, __shfl_xor(m, s, 16));
    float e = __expf(o - m);
    float se = e;
    for (int s = 8; s >= 1; s >>= 1) se += __shfl_xor(se, s, 16);
    out[(size_t)gidx * OUTC + t] = o - m - __logf(se);
  }
}

}  // namespace

extern "C" void kernel_launch(void* const* d_in, const int* in_sizes, int n_in,
                              void* d_out, int out_size, void* d_ws, size_t ws_size,
                              hipStream_t stream) {
  const float* x     = (const float*)d_in[0];
  const int*   ei    = (const int*)d_in[1];
  const int*   batch = (const int*)d_in[2];
  const float* W1_0  = (const float*)d_in[4];
  const float* b1_0  = (const float*)d_in[5];
  const float* g_0   = (const float*)d_in[6];
  const float* bt_0  = (const float*)d_in[7];
  const float* W2_0  = (const float*)d_in[8];
  const float* b2_0  = (const float*)d_in[9];
  const float* W1s   = (const float*)d_in[10];
  const float* b1s   = (const float*)d_in[11];
  const float* gs    = (const float*)d_in[12];
  const float* bts   = (const float*)d_in[13];
  const float* W2s   = (const float*)d_in[14];
  const float* b2s   = (const float*)d_in[15];
  const float* lin1W = (const float*)d_in[16];
  const float* lin1b = (const float*)d_in[17];
  const float* lin2W = (const float*)d_in[18];
  const float* lin2b = (const float*)d_in[19];

  float* out_ls = (float*)d_out;              // [256,16]
  float* x1_out = (float*)d_out + NG * OUTC;  // [40000,128] f32

  char* w = (char*)d_ws;
  auto alloc = [&](size_t bytes) -> void* {
    void* p = (void*)w;
    w += (bytes + 255) & ~(size_t)255;
    return p;
  };
  int*    deg      = (int*)alloc((size_t)(N + 64) * 4);
  int*    counter  = deg + N;
  int*    start    = (int*)alloc((size_t)N * 4);
  int*    cursor   = (int*)alloc((size_t)N * 4);
  int*    col      = (int*)alloc((size_t)E * 4);
  ushort* xb       = (ushort*)alloc((size_t)N * DIM * 2);   // layer input (bf16)
  ushort* act      = (ushort*)alloc((size_t)N * DIM * 2);   // t -> h -> a (in place)
  ushort* Wt       = (ushort*)alloc((size_t)10 * DIM * DIM * 2);
  float*  statsAll = (float*)alloc((size_t)(5 * 2 * DIM + NG * DIM) * 4);
  float*  pooled   = statsAll + 5 * 2 * DIM;

  const int* src = ei;
  const int* dst = ei + E;

  hipMemsetAsync(deg, 0, (size_t)(N + 64) * 4, stream);
  hipMemsetAsync(statsAll, 0, (size_t)(5 * 2 * DIM + NG * DIM) * 4, stream);

  // converts
  cvt_f32_bf16<<<(N * DIM / 8) / 256, 256, 0, stream>>>(x, xb);  // 2500 blocks
  transpose_weights<<<10 * DIM, 64, 0, stream>>>(W1_0, W2_0, W1s, W2s, Wt);

  // CSR
  hist_kernel<<<E / 256, 256, 0, stream>>>(dst, deg);
  alloc_kernel<<<(N + 255) / 256, 256, 0, stream>>>(deg, counter, start, cursor);
  fill_kernel<<<E / 256, 256, 0, stream>>>(src, dst, cursor, col);

  // 5 GIN layers
  for (int l = 0; l < 5; ++l) {
    const float* b1 = (l == 0) ? b1_0 : b1s + (size_t)(l - 1) * DIM;
    const float* gg = (l == 0) ? g_0  : gs  + (size_t)(l - 1) * DIM;
    const float* bb = (l == 0) ? bt_0 : bts + (size_t)(l - 1) * DIM;
    const float* b2 = (l == 0) ? b2_0 : b2s + (size_t)(l - 1) * DIM;
    const ushort* Wt1 = Wt + (size_t)(2 * l) * DIM * DIM;
    const ushort* Wt2 = Wt + (size_t)(2 * l + 1) * DIM * DIM;
    float* stats = statsAll + (size_t)l * 2 * DIM;

    aggregate_kernel<<<(N * 16 + 255) / 256, 256, 0, stream>>>(xb, start, deg, col, act);
    mfma_gemm<1, 0, 0><<<N / 32, 256, 0, stream>>>(act, Wt1, b1, stats, act, nullptr);
    bn_apply<<<(N / 8) * 32 / 256, 256, 0, stream>>>(act, stats, gg, bb);
    if (l == 4)
      mfma_gemm<0, 1, 1><<<N / 32, 256, 0, stream>>>(act, Wt2, b2, nullptr, nullptr, x1_out);
    else
      mfma_gemm<0, 1, 0><<<N / 32, 256, 0, stream>>>(act, Wt2, b2, nullptr, xb, nullptr);
  }

  // pooling + MLP head
  {
    int groups = (N + 63) / 64;
    int blocks = (groups * 32 + 255) / 256;
    pool_kernel<<<blocks, 256, 0, stream>>>(x1_out, batch, pooled);
  }
  mlp_kernel<<<NG, 128, 0, stream>>>(pooled, lin1W, lin1b, lin2W, lin2b, out_ls);
}

// Round 4
// 355.049 us; speedup vs baseline: 5.2103x; 1.5062x over previous
//
#include <hip/hip_runtime.h>

namespace {

constexpr int N    = 40000;
constexpr int E    = 640000;
constexpr int DIM  = 128;
constexpr int NG   = 256;
constexpr int OUTC = 16;
constexpr float BN_EPS = 1e-5f;

typedef __attribute__((ext_vector_type(8))) short bf16x8;
typedef __attribute__((ext_vector_type(4))) float f32x4;

__device__ __forceinline__ void atomAddF(float* p, float v) {
  unsafeAtomicAdd(p, v);
}

// round-to-nearest-even f32 -> bf16 (as uint in low 16)
__device__ __forceinline__ unsigned b16r(float f) {
  unsigned u = __float_as_uint(f);
  return (u + 0x7fffu + ((u >> 16) & 1u)) >> 16;
}
__device__ __forceinline__ unsigned pack2(float a, float b) {
  return b16r(a) | (b16r(b) << 16);
}
__device__ __forceinline__ void add8(float* a, const uint4 v) {
  a[0] += __uint_as_float(v.x << 16);
  a[1] += __uint_as_float(v.x & 0xffff0000u);
  a[2] += __uint_as_float(v.y << 16);
  a[3] += __uint_as_float(v.y & 0xffff0000u);
  a[4] += __uint_as_float(v.z << 16);
  a[5] += __uint_as_float(v.z & 0xffff0000u);
  a[6] += __uint_as_float(v.w << 16);
  a[7] += __uint_as_float(v.w & 0xffff0000u);
}

// BN+relu on 8 packed bf16 values, repacked to bf16x8 (same rounding as R3 bn_apply)
__device__ __forceinline__ bf16x8 bnrelu8(bf16x8 a, const float* sc, const float* sh) {
  union { bf16x8 v; unsigned u[4]; } in, out;
  in.v = a;
#pragma unroll
  for (int p = 0; p < 4; ++p) {
    float lo = __uint_as_float(in.u[p] << 16);
    float hi = __uint_as_float(in.u[p] & 0xffff0000u);
    lo = fmaxf(fmaf(lo, sc[2 * p], sh[2 * p]), 0.f);
    hi = fmaxf(fmaf(hi, sc[2 * p + 1], sh[2 * p + 1]), 0.f);
    out.u[p] = pack2(lo, hi);
  }
  return out.v;
}

// ---------------- converts ----------------

__global__ __launch_bounds__(256) void cvt_f32_bf16(const float* __restrict__ in,
                                                    ushort* __restrict__ out) {
  const int i = blockIdx.x * 256 + threadIdx.x;
  const float4* __restrict__ in4 = (const float4*)in;
  float4 v0 = in4[(size_t)i * 2], v1 = in4[(size_t)i * 2 + 1];
  uint4 o = {pack2(v0.x, v0.y), pack2(v0.z, v0.w), pack2(v1.x, v1.y), pack2(v1.z, v1.w)};
  ((uint4*)out)[i] = o;
}

// W[k][c] f32 -> Wt[m][c][k] bf16   (10 matrices of 128x128)
__global__ __launch_bounds__(64) void transpose_weights(const float* __restrict__ W1_0,
                                                        const float* __restrict__ W2_0,
                                                        const float* __restrict__ W1s,
                                                        const float* __restrict__ W2s,
                                                        ushort* __restrict__ Wt) {
  const int m    = blockIdx.x >> 7;   // 0..9
  const int c    = blockIdx.x & 127;
  const int lane = threadIdx.x;       // 0..63
  const int l    = m >> 1;
  const float* W;
  if (l == 0) W = (m & 1) ? W2_0 : W1_0;
  else        W = ((m & 1) ? W2s : W1s) + (size_t)(l - 1) * DIM * DIM;
  const int k = lane * 2;
  float f0 = W[(size_t)k * DIM + c];
  float f1 = W[(size_t)(k + 1) * DIM + c];
  ((unsigned*)Wt)[((size_t)m * DIM + c) * 64 + lane] = pack2(f0, f1);
}

// ---------------- CSR build (order-free segments) ----------------

__global__ void hist_kernel(const int* __restrict__ dst, int* __restrict__ deg) {
  int e = blockIdx.x * blockDim.x + threadIdx.x;
  if (e < E) atomicAdd(&deg[dst[e]], 1);
}

__global__ __launch_bounds__(256) void alloc_kernel(const int* __restrict__ deg,
                                                    int* __restrict__ counter,
                                                    int* __restrict__ start,
                                                    int* __restrict__ cursor) {
  const int i    = blockIdx.x * blockDim.x + threadIdx.x;
  const int lane = threadIdx.x & 63;
  int d = (i < N) ? deg[i] : 0;
  int incl = d;
#pragma unroll
  for (int o = 1; o < 64; o <<= 1) {
    int v = __shfl_up(incl, o, 64);
    if (lane >= o) incl += v;
  }
  int base = 0;
  if (lane == 63) base = atomicAdd(counter, incl);
  base = __shfl(base, 63, 64);
  int s0 = base + incl - d;
  if (i < N) { start[i] = s0; cursor[i] = s0; }
}

__global__ void fill_kernel(const int* __restrict__ src, const int* __restrict__ dst,
                            int* __restrict__ cursor, int* __restrict__ col) {
  int e = blockIdx.x * blockDim.x + threadIdx.x;
  if (e < E) {
    int p = atomicAdd(&cursor[dst[e]], 1);
    col[p] = src[e];
  }
}

// ---------------- fused GIN part 1: gather -> LDS -> MFMA(W1) + bias + stats ------
// 512 thr = 8 waves; 32 nodes/block; t tile in 8 KB LDS (bf16, XOR-swizzled 16B chunks).
// Gather: 16 lanes/node (256 B per neighbor). GEMM: wave w = 32 rows x cols [16w,16w+16).

__global__ __launch_bounds__(512) void gin1_fused(const ushort* __restrict__ xb,
                                                  const int* __restrict__ start,
                                                  const int* __restrict__ deg,
                                                  const int* __restrict__ col,
                                                  const ushort* __restrict__ Wt1,
                                                  const float* __restrict__ b1,
                                                  ushort* __restrict__ h,
                                                  float* __restrict__ stats8) {
  __shared__ uint4 tile4[32 * 16];
  const int tid   = threadIdx.x;
  const int node0 = blockIdx.x * 32;

  // ---- phase 1: gather ----
  {
    const int r = tid >> 4;   // 0..31
    const int l = tid & 15;
    const int node = node0 + r;
    const uint4* __restrict__ x16 = (const uint4*)xb;
    float a[8] = {0, 0, 0, 0, 0, 0, 0, 0};
    add8(a, x16[(size_t)node * 16 + l]);
    const int b = start[node], n = deg[node];
    int k = 0;
    for (; k + 4 <= n; k += 4) {
      int j0 = col[b + k], j1 = col[b + k + 1], j2 = col[b + k + 2], j3 = col[b + k + 3];
      uint4 v0 = x16[(size_t)j0 * 16 + l];
      uint4 v1 = x16[(size_t)j1 * 16 + l];
      uint4 v2 = x16[(size_t)j2 * 16 + l];
      uint4 v3 = x16[(size_t)j3 * 16 + l];
      add8(a, v0); add8(a, v1); add8(a, v2); add8(a, v3);
    }
    for (; k < n; ++k) add8(a, x16[(size_t)col[b + k] * 16 + l]);
    uint4 o = {pack2(a[0], a[1]), pack2(a[2], a[3]), pack2(a[4], a[5]), pack2(a[6], a[7])};
    tile4[r * 16 + (l ^ ((r << 1) & 15))] = o;
  }
  __syncthreads();

  // ---- phase 2: GEMM ----
  const int lane = tid & 63;
  const int c0   = __builtin_amdgcn_readfirstlane((tid >> 6) * 16);
  const int lr   = lane & 15;
  const int lg   = lane >> 4;

  const ushort* __restrict__ brow = Wt1 + (size_t)(c0 + lr) * DIM + lg * 8;
  const bf16x8* __restrict__ tb   = (const bf16x8*)tile4;

  f32x4 acc0 = {0, 0, 0, 0}, acc1 = {0, 0, 0, 0};
#pragma unroll
  for (int ks = 0; ks < 4; ++ks) {
    bf16x8 b  = *(const bf16x8*)(brow + ks * 32);
    const int r0 = lr, r1 = lr + 16;
    bf16x8 a0 = tb[r0 * 16 + ((lg + ks * 4) ^ ((r0 << 1) & 15))];
    bf16x8 a1 = tb[r1 * 16 + ((lg + ks * 4) ^ ((r1 << 1) & 15))];
    acc0 = __builtin_amdgcn_mfma_f32_16x16x32_bf16(a0, b, acc0, 0, 0, 0);
    acc1 = __builtin_amdgcn_mfma_f32_16x16x32_bf16(a1, b, acc1, 0, 0, 0);
  }

  const float bia = b1[c0 + lr];
  float s = 0.f, q = 0.f;
  f32x4 accs[2] = {acc0, acc1};
#pragma unroll
  for (int rf = 0; rf < 2; ++rf) {
#pragma unroll
    for (int rg = 0; rg < 4; ++rg) {
      float v = accs[rf][rg] + bia;
      const int row = node0 + rf * 16 + lg * 4 + rg;
      h[(size_t)row * DIM + c0 + lr] = (ushort)b16r(v);
      s += v; q = fmaf(v, v, q);
    }
  }
  s += __shfl_xor(s, 16); s += __shfl_xor(s, 32);
  q += __shfl_xor(q, 16); q += __shfl_xor(q, 32);
  if (lg == 0) {
    float* st = stats8 + (blockIdx.x & 7) * 2 * DIM;
    atomAddF(&st[c0 + lr], s);
    atomAddF(&st[DIM + c0 + lr], q);
  }
}

// ---------------- fused GIN part 2: BN(+relu) on A-load -> MFMA(W2) + bias + relu -
// 256 thr = 4 waves; 32 rows/block; wave covers 32 rows x 32 cols.

template <int F32OUT>
__global__ __launch_bounds__(256) void gin2_fused(const ushort* __restrict__ h,
                                                  const float* __restrict__ stats8,
                                                  const float* __restrict__ gamma,
                                                  const float* __restrict__ beta,
                                                  const ushort* __restrict__ Wt2,
                                                  const float* __restrict__ b2,
                                                  ushort* __restrict__ outb,
                                                  float* __restrict__ outf) {
  __shared__ float lsc[DIM], lsh[DIM];
  const int tid = threadIdx.x;
  if (tid < DIM) {
    float s = 0.f, q = 0.f;
#pragma unroll
    for (int p = 0; p < 8; ++p) {
      s += stats8[p * 2 * DIM + tid];
      q += stats8[p * 2 * DIM + DIM + tid];
    }
    const float inv_n = 1.0f / N;
    float mu  = s * inv_n;
    float var = q * inv_n - mu * mu;
    float sc  = gamma[tid] * rsqrtf(var + BN_EPS);
    lsc[tid] = sc;
    lsh[tid] = beta[tid] - mu * sc;
  }
  __syncthreads();

  const int lane = tid & 63;
  const int c0   = __builtin_amdgcn_readfirstlane((tid >> 6) * 32);
  const int lr   = lane & 15;
  const int lg   = lane >> 4;
  const int row0 = blockIdx.x * 32;

  const ushort* __restrict__ arow = h + (size_t)(row0 + lr) * DIM + lg * 8;
  const ushort* __restrict__ brow = Wt2 + (size_t)(c0 + lr) * DIM + lg * 8;

  f32x4 acc00 = {0, 0, 0, 0}, acc01 = {0, 0, 0, 0}, acc10 = {0, 0, 0, 0}, acc11 = {0, 0, 0, 0};

#pragma unroll
  for (int ks = 0; ks < 4; ++ks) {
    const int ch0 = lg * 8 + ks * 32;
    float sc[8], sh[8];
    *(float4*)(sc)     = *(const float4*)&lsc[ch0];
    *(float4*)(sc + 4) = *(const float4*)&lsc[ch0 + 4];
    *(float4*)(sh)     = *(const float4*)&lsh[ch0];
    *(float4*)(sh + 4) = *(const float4*)&lsh[ch0 + 4];
    bf16x8 a0 = bnrelu8(*(const bf16x8*)(arow + ks * 32), sc, sh);
    bf16x8 a1 = bnrelu8(*(const bf16x8*)(arow + 16 * DIM + ks * 32), sc, sh);
    bf16x8 b0 = *(const bf16x8*)(brow + ks * 32);
    bf16x8 b1 = *(const bf16x8*)(brow + 16 * DIM + ks * 32);
    acc00 = __builtin_amdgcn_mfma_f32_16x16x32_bf16(a0, b0, acc00, 0, 0, 0);
    acc01 = __builtin_amdgcn_mfma_f32_16x16x32_bf16(a0, b1, acc01, 0, 0, 0);
    acc10 = __builtin_amdgcn_mfma_f32_16x16x32_bf16(a1, b0, acc10, 0, 0, 0);
    acc11 = __builtin_amdgcn_mfma_f32_16x16x32_bf16(a1, b1, acc11, 0, 0, 0);
  }

  const float bia0 = b2[c0 + lr];
  const float bia1 = b2[c0 + 16 + lr];
  f32x4 accs[2][2] = {{acc00, acc01}, {acc10, acc11}};
#pragma unroll
  for (int rf = 0; rf < 2; ++rf) {
#pragma unroll
    for (int cf = 0; cf < 2; ++cf) {
      const int colidx = c0 + cf * 16 + lr;
      const float bb = cf ? bia1 : bia0;
#pragma unroll
      for (int rg = 0; rg < 4; ++rg) {
        float v = fmaxf(accs[rf][cf][rg] + bb, 0.f);
        const int row = row0 + rf * 16 + lg * 4 + rg;
        if (F32OUT) outf[(size_t)row * DIM + colidx] = v;
        else        outb[(size_t)row * DIM + colidx] = (ushort)b16r(v);
      }
    }
  }
}

// ---------------- segment pooling over sorted batch -------------------------------

__global__ __launch_bounds__(256) void pool_kernel(const float* __restrict__ x1,
                                                   const int* __restrict__ batch,
                                                   float* __restrict__ pooled) {
  const int grp  = (blockIdx.x * blockDim.x + threadIdx.x) >> 5;
  const int lane = threadIdx.x & 31;
  const int node0 = grp * 64;
  if (node0 >= N) return;
  const int end = (node0 + 64 < N) ? (node0 + 64) : N;
  float4 acc = {0, 0, 0, 0};
  int cur = batch[node0];
  for (int n = node0; n < end; ++n) {
    int b = batch[n];
    if (b != cur) {
      atomAddF(&pooled[(size_t)cur * DIM + lane * 4 + 0], acc.x);
      atomAddF(&pooled[(size_t)cur * DIM + lane * 4 + 1], acc.y);
      atomAddF(&pooled[(size_t)cur * DIM + lane * 4 + 2], acc.z);
      atomAddF(&pooled[(size_t)cur * DIM + lane * 4 + 3], acc.w);
      acc = {0, 0, 0, 0};
      cur = b;
    }
    float4 v = ((const float4*)x1)[(size_t)n * 32 + lane];
    acc.x += v.x; acc.y += v.y; acc.z += v.z; acc.w += v.w;
  }
  atomAddF(&pooled[(size_t)cur * DIM + lane * 4 + 0], acc.x);
  atomAddF(&pooled[(size_t)cur * DIM + lane * 4 + 1], acc.y);
  atomAddF(&pooled[(size_t)cur * DIM + lane * 4 + 2], acc.z);
  atomAddF(&pooled[(size_t)cur * DIM + lane * 4 + 3], acc.w);
}

// ---------------- final MLP + log_softmax -----------------------------------------

__global__ __launch_bounds__(128) void mlp_kernel(const float* __restrict__ pooled,
                                                  const float* __restrict__ W1,
                                                  const float* __restrict__ b1,
                                                  const float* __restrict__ W2,
                                                  const float* __restrict__ b2,
                                                  float* __restrict__ out) {
  const int gidx = blockIdx.x;
  const int t    = threadIdx.x;
  __shared__ float p[DIM], a1[DIM];
  p[t] = pooled[(size_t)gidx * DIM + t];
  __syncthreads();
  float acc = b1[t];
  for (int k = 0; k < DIM; ++k) acc = fmaf(p[k], W1[(size_t)k * DIM + t], acc);
  a1[t] = fmaxf(acc, 0.f);
  __syncthreads();
  if (t < OUTC) {
    float o = b2[t];
    for (int k = 0; k < DIM; ++k) o = fmaf(a1[k], W2[(size_t)k * OUTC + t], o);
    float m = o;
    for (int s = 8; s >= 1; s >>= 1) m = fmaxf(m, __shfl_xor(m, s, 16));
    float e = __expf(o - m);
    float se = e;
    for (int s = 8; s >= 1; s >>= 1) se += __shfl_xor(se, s, 16);
    out[(size_t)gidx * OUTC + t] = o - m - __logf(se);
  }
}

}  // namespace

extern "C" void kernel_launch(void* const* d_in, const int* in_sizes, int n_in,
                              void* d_out, int out_size, void* d_ws, size_t ws_size,
                              hipStream_t stream) {
  const float* x     = (const float*)d_in[0];
  const int*   ei    = (const int*)d_in[1];
  const int*   batch = (const int*)d_in[2];
  const float* W1_0  = (const float*)d_in[4];
  const float* b1_0  = (const float*)d_in[5];
  const float* g_0   = (const float*)d_in[6];
  const float* bt_0  = (const float*)d_in[7];
  const float* W2_0  = (const float*)d_in[8];
  const float* b2_0  = (const float*)d_in[9];
  const float* W1s   = (const float*)d_in[10];
  const float* b1s   = (const float*)d_in[11];
  const float* gs    = (const float*)d_in[12];
  const float* bts   = (const float*)d_in[13];
  const float* W2s   = (const float*)d_in[14];
  const float* b2s   = (const float*)d_in[15];
  const float* lin1W = (const float*)d_in[16];
  const float* lin1b = (const float*)d_in[17];
  const float* lin2W = (const float*)d_in[18];
  const float* lin2b = (const float*)d_in[19];

  float* out_ls = (float*)d_out;              // [256,16]
  float* x1_out = (float*)d_out + NG * OUTC;  // [40000,128] f32

  char* w = (char*)d_ws;
  auto alloc = [&](size_t bytes) -> void* {
    void* p = (void*)w;
    w += (bytes + 255) & ~(size_t)255;
    return p;
  };
  int*    deg      = (int*)alloc((size_t)(N + 64) * 4);
  int*    counter  = deg + N;
  int*    start    = (int*)alloc((size_t)N * 4);
  int*    cursor   = (int*)alloc((size_t)N * 4);
  int*    col      = (int*)alloc((size_t)E * 4);
  ushort* xb       = (ushort*)alloc((size_t)N * DIM * 2);   // layer input (bf16)
  ushort* act      = (ushort*)alloc((size_t)N * DIM * 2);   // h buffer
  ushort* Wt       = (ushort*)alloc((size_t)10 * DIM * DIM * 2);
  float*  statsAll = (float*)alloc((size_t)(5 * 8 * 2 * DIM + NG * DIM) * 4);
  float*  pooled   = statsAll + 5 * 8 * 2 * DIM;

  const int* src = ei;
  const int* dst = ei + E;

  hipMemsetAsync(deg, 0, (size_t)(N + 64) * 4, stream);
  hipMemsetAsync(statsAll, 0, (size_t)(5 * 8 * 2 * DIM + NG * DIM) * 4, stream);

  // converts
  cvt_f32_bf16<<<(N * DIM / 8) / 256, 256, 0, stream>>>(x, xb);
  transpose_weights<<<10 * DIM, 64, 0, stream>>>(W1_0, W2_0, W1s, W2s, Wt);

  // CSR
  hist_kernel<<<E / 256, 256, 0, stream>>>(dst, deg);
  alloc_kernel<<<(N + 255) / 256, 256, 0, stream>>>(deg, counter, start, cursor);
  fill_kernel<<<E / 256, 256, 0, stream>>>(src, dst, cursor, col);

  // 5 GIN layers: gin1_fused (gather+W1+stats) -> gin2_fused (BN+relu+W2+relu)
  for (int l = 0; l < 5; ++l) {
    const float* b1 = (l == 0) ? b1_0 : b1s + (size_t)(l - 1) * DIM;
    const float* gg = (l == 0) ? g_0  : gs  + (size_t)(l - 1) * DIM;
    const float* bb = (l == 0) ? bt_0 : bts + (size_t)(l - 1) * DIM;
    const float* b2 = (l == 0) ? b2_0 : b2s + (size_t)(l - 1) * DIM;
    const ushort* Wt1 = Wt + (size_t)(2 * l) * DIM * DIM;
    const ushort* Wt2 = Wt + (size_t)(2 * l + 1) * DIM * DIM;
    float* stats8 = statsAll + (size_t)l * 8 * 2 * DIM;

    gin1_fused<<<N / 32, 512, 0, stream>>>(xb, start, deg, col, Wt1, b1, act, stats8);
    if (l == 4)
      gin2_fused<1><<<N / 32, 256, 0, stream>>>(act, stats8, gg, bb, Wt2, b2, nullptr, x1_out);
    else
      gin2_fused<0><<<N / 32, 256, 0, stream>>>(act, stats8, gg, bb, Wt2, b2, xb, nullptr);
  }

  // pooling + MLP head
  {
    int groups = (N + 63) / 64;
    int blocks = (groups * 32 + 255) / 256;
    pool_kernel<<<blocks, 256, 0, stream>>>(x1_out, batch, pooled);
  }
  mlp_kernel<<<NG, 128, 0, stream>>>(pooled, lin1W, lin1b, lin2W, lin2b, out_ls);
}

// Round 5
// 316.459 us; speedup vs baseline: 5.8457x; 1.1219x over previous
//
#include <hip/hip_runtime.h>

namespace {

constexpr int N    = 40000;
constexpr int E    = 640000;
constexpr int DIM  = 128;
constexpr int NG   = 256;
constexpr int OUTC = 16;
constexpr float BN_EPS = 1e-5f;

typedef __attribute__((ext_vector_type(8))) short bf16x8;
typedef __attribute__((ext_vector_type(4))) float f32x4;
typedef __attribute__((ext_vector_type(2))) float f32x2;

__device__ __forceinline__ void atomAddF(float* p, float v) {
  unsafeAtomicAdd(p, v);
}

// round-to-nearest-even f32 -> bf16 (as uint in low 16)
__device__ __forceinline__ unsigned b16r(float f) {
  unsigned u = __float_as_uint(f);
  return (u + 0x7fffu + ((u >> 16) & 1u)) >> 16;
}
__device__ __forceinline__ unsigned pack2(float a, float b) {
  return b16r(a) | (b16r(b) << 16);
}

// fp8 e4m3 (OCP) helpers — hardware cvt
__device__ __forceinline__ unsigned pk4_fp8(float4 v) {
  unsigned u = __builtin_amdgcn_cvt_pk_fp8_f32(v.x, v.y, 0, false);
  u = __builtin_amdgcn_cvt_pk_fp8_f32(v.z, v.w, u, true);
  return u;
}
__device__ __forceinline__ void addfp8x4(float* a, unsigned u) {
  f32x2 lo = __builtin_amdgcn_cvt_pk_f32_fp8(u, false);
  f32x2 hi = __builtin_amdgcn_cvt_pk_f32_fp8(u, true);
  a[0] += lo[0]; a[1] += lo[1]; a[2] += hi[0]; a[3] += hi[1];
}
__device__ __forceinline__ void add16(float* a, const uint4 v) {
  addfp8x4(a, v.x); addfp8x4(a + 4, v.y); addfp8x4(a + 8, v.z); addfp8x4(a + 12, v.w);
}

// BN+relu on 8 packed bf16 values, repacked to bf16x8
__device__ __forceinline__ bf16x8 bnrelu8(bf16x8 a, const float* sc, const float* sh) {
  union { bf16x8 v; unsigned u[4]; } in, out;
  in.v = a;
#pragma unroll
  for (int p = 0; p < 4; ++p) {
    float lo = __uint_as_float(in.u[p] << 16);
    float hi = __uint_as_float(in.u[p] & 0xffff0000u);
    lo = fmaxf(fmaf(lo, sc[2 * p], sh[2 * p]), 0.f);
    hi = fmaxf(fmaf(hi, sc[2 * p + 1], sh[2 * p + 1]), 0.f);
    out.u[p] = pack2(lo, hi);
  }
  return out.v;
}

// ---------------- prep: cvt x->fp8  |  degree histogram  |  weight transpose -----
constexpr int CVT_B   = (N * DIM / 4) / 256;  // 5000
constexpr int HIST_B  = E / 256;              // 2500
constexpr int TRANS_B = 10 * DIM / 4;         // 320  (4 matrix-cols per block)

__global__ __launch_bounds__(256) void prep_kernel(const float* __restrict__ x,
                                                   unsigned char* __restrict__ xf8,
                                                   const int* __restrict__ dst,
                                                   int* __restrict__ deg,
                                                   const float* __restrict__ W1_0,
                                                   const float* __restrict__ W2_0,
                                                   const float* __restrict__ W1s,
                                                   const float* __restrict__ W2s,
                                                   ushort* __restrict__ Wt) {
  const int b = blockIdx.x;
  if (b < CVT_B) {
    const int i = b * 256 + threadIdx.x;          // one float4 -> 4 fp8
    float4 v = ((const float4*)x)[i];
    ((unsigned*)xf8)[i] = pk4_fp8(v);
  } else if (b < CVT_B + HIST_B) {
    const int e = (b - CVT_B) * 256 + threadIdx.x;
    atomicAdd(&deg[dst[e]], 1);
  } else {
    const int ob   = (b - CVT_B - HIST_B) * 4 + (threadIdx.x >> 6);  // 0..1279
    const int lane = threadIdx.x & 63;
    const int m = ob >> 7;   // matrix 0..9
    const int c = ob & 127;  // out-channel
    const int l = m >> 1;
    const float* W;
    if (l == 0) W = (m & 1) ? W2_0 : W1_0;
    else        W = ((m & 1) ? W2s : W1s) + (size_t)(l - 1) * DIM * DIM;
    const int k = lane * 2;
    float f0 = W[(size_t)k * DIM + c];
    float f1 = W[(size_t)(k + 1) * DIM + c];
    ((unsigned*)Wt)[((size_t)m * DIM + c) * 64 + lane] = pack2(f0, f1);
  }
}

// ---------------- CSR build (order-free segments) ----------------

__global__ __launch_bounds__(256) void alloc_kernel(const int* __restrict__ deg,
                                                    int* __restrict__ counter,
                                                    int* __restrict__ start,
                                                    int* __restrict__ cursor) {
  const int i    = blockIdx.x * blockDim.x + threadIdx.x;
  const int lane = threadIdx.x & 63;
  int d = (i < N) ? deg[i] : 0;
  int incl = d;
#pragma unroll
  for (int o = 1; o < 64; o <<= 1) {
    int v = __shfl_up(incl, o, 64);
    if (lane >= o) incl += v;
  }
  int base = 0;
  if (lane == 63) base = atomicAdd(counter, incl);
  base = __shfl(base, 63, 64);
  int s0 = base + incl - d;
  if (i < N) { start[i] = s0; cursor[i] = s0; }
}

__global__ void fill_kernel(const int* __restrict__ src, const int* __restrict__ dst,
                            int* __restrict__ cursor, int* __restrict__ col) {
  int e = blockIdx.x * blockDim.x + threadIdx.x;
  if (e < E) {
    int p = atomicAdd(&cursor[dst[e]], 1);
    col[p] = src[e];
  }
}

// ---------------- fused GIN part 1: fp8 gather -> LDS(bf16) -> MFMA(W1) + stats ---
// 512 thr; 64 nodes/block; 8 lanes/node (16B = 16 fp8 per lane); 16 KB LDS tile.
// GEMM: 8 waves; wave w: rows (w>>2)*32..+32, cols (w&3)*32..+32.

__global__ __launch_bounds__(512) void gin1_fused(const unsigned char* __restrict__ xf8,
                                                  const int* __restrict__ start,
                                                  const int* __restrict__ deg,
                                                  const int* __restrict__ col,
                                                  const ushort* __restrict__ Wt1,
                                                  const float* __restrict__ b1,
                                                  ushort* __restrict__ h,
                                                  float* __restrict__ stats8) {
  __shared__ uint4 tile4[64 * 16];  // 16 KB, XOR-swizzled 16B chunks
  const int tid   = threadIdx.x;
  const int node0 = blockIdx.x * 64;

  // ---- phase 1: gather ----
  {
    const int r = tid >> 3;   // 0..63
    const int l = tid & 7;    // 16B chunk of the 128B row
    const int node = node0 + r;
    const uint4* __restrict__ x16 = (const uint4*)xf8;
    float a[16];
#pragma unroll
    for (int i = 0; i < 16; ++i) a[i] = 0.f;
    add16(a, x16[(size_t)node * 8 + l]);  // self
    const int b = start[node], n = deg[node];
    int k = 0;
    for (; k + 4 <= n; k += 4) {
      int j0 = col[b + k], j1 = col[b + k + 1], j2 = col[b + k + 2], j3 = col[b + k + 3];
      uint4 v0 = x16[(size_t)j0 * 8 + l];
      uint4 v1 = x16[(size_t)j1 * 8 + l];
      uint4 v2 = x16[(size_t)j2 * 8 + l];
      uint4 v3 = x16[(size_t)j3 * 8 + l];
      add16(a, v0); add16(a, v1); add16(a, v2); add16(a, v3);
    }
    for (; k < n; ++k) add16(a, x16[(size_t)col[b + k] * 8 + l]);
    uint4 o0 = {pack2(a[0], a[1]), pack2(a[2], a[3]), pack2(a[4], a[5]), pack2(a[6], a[7])};
    uint4 o1 = {pack2(a[8], a[9]), pack2(a[10], a[11]), pack2(a[12], a[13]), pack2(a[14], a[15])};
    const int sw = (r << 1) & 15;
    tile4[r * 16 + ((2 * l) ^ sw)]     = o0;
    tile4[r * 16 + ((2 * l + 1) ^ sw)] = o1;
  }
  __syncthreads();

  // ---- phase 2: GEMM ----
  const int w    = tid >> 6;
  const int lane = tid & 63;
  const int rh   = __builtin_amdgcn_readfirstlane(w >> 2);        // row half
  const int c0   = __builtin_amdgcn_readfirstlane((w & 3) * 32);  // col slice
  const int lr   = lane & 15;
  const int lg   = lane >> 4;

  const ushort* __restrict__ brow = Wt1 + (size_t)(c0 + lr) * DIM + lg * 8;
  const bf16x8* __restrict__ tb   = (const bf16x8*)tile4;

  f32x4 acc00 = {0, 0, 0, 0}, acc01 = {0, 0, 0, 0}, acc10 = {0, 0, 0, 0}, acc11 = {0, 0, 0, 0};
  const int r0 = rh * 32 + lr, r1 = rh * 32 + 16 + lr;
  const int sw0 = (r0 << 1) & 15, sw1 = (r1 << 1) & 15;
#pragma unroll
  for (int ks = 0; ks < 4; ++ks) {
    bf16x8 a0 = tb[r0 * 16 + ((lg + ks * 4) ^ sw0)];
    bf16x8 a1 = tb[r1 * 16 + ((lg + ks * 4) ^ sw1)];
    bf16x8 b0 = *(const bf16x8*)(brow + ks * 32);
    bf16x8 b1v = *(const bf16x8*)(brow + 16 * DIM + ks * 32);
    acc00 = __builtin_amdgcn_mfma_f32_16x16x32_bf16(a0, b0, acc00, 0, 0, 0);
    acc01 = __builtin_amdgcn_mfma_f32_16x16x32_bf16(a0, b1v, acc01, 0, 0, 0);
    acc10 = __builtin_amdgcn_mfma_f32_16x16x32_bf16(a1, b0, acc10, 0, 0, 0);
    acc11 = __builtin_amdgcn_mfma_f32_16x16x32_bf16(a1, b1v, acc11, 0, 0, 0);
  }

  const float bia0 = b1[c0 + lr];
  const float bia1 = b1[c0 + 16 + lr];
  float s[2] = {0, 0}, q[2] = {0, 0};
  f32x4 accs[2][2] = {{acc00, acc01}, {acc10, acc11}};
#pragma unroll
  for (int rf = 0; rf < 2; ++rf) {
#pragma unroll
    for (int cf = 0; cf < 2; ++cf) {
      const int colidx = c0 + cf * 16 + lr;
      const float bb = cf ? bia1 : bia0;
#pragma unroll
      for (int rg = 0; rg < 4; ++rg) {
        float v = accs[rf][cf][rg] + bb;
        const int row = node0 + rh * 32 + rf * 16 + lg * 4 + rg;
        h[(size_t)row * DIM + colidx] = (ushort)b16r(v);
        s[cf] += v; q[cf] = fmaf(v, v, q[cf]);
      }
    }
  }
#pragma unroll
  for (int cf = 0; cf < 2; ++cf) {
    float ss = s[cf], qq = q[cf];
    ss += __shfl_xor(ss, 16); ss += __shfl_xor(ss, 32);
    qq += __shfl_xor(qq, 16); qq += __shfl_xor(qq, 32);
    if (lg == 0) {
      float* st = stats8 + (blockIdx.x & 7) * 2 * DIM;
      atomAddF(&st[c0 + cf * 16 + lr], ss);
      atomAddF(&st[DIM + c0 + cf * 16 + lr], qq);
    }
  }
}

// ---------------- fused GIN part 2: BN(+relu) on A-load -> MFMA(W2) -> fp8/f32 ----

template <int F32OUT>
__global__ __launch_bounds__(256) void gin2_fused(const ushort* __restrict__ h,
                                                  const float* __restrict__ stats8,
                                                  const float* __restrict__ gamma,
                                                  const float* __restrict__ beta,
                                                  const ushort* __restrict__ Wt2,
                                                  const float* __restrict__ b2,
                                                  unsigned char* __restrict__ xf8,
                                                  float* __restrict__ outf) {
  __shared__ float lsc[DIM], lsh[DIM];
  const int tid = threadIdx.x;
  if (tid < DIM) {
    float s = 0.f, q = 0.f;
#pragma unroll
    for (int p = 0; p < 8; ++p) {
      s += stats8[p * 2 * DIM + tid];
      q += stats8[p * 2 * DIM + DIM + tid];
    }
    const float inv_n = 1.0f / N;
    float mu  = s * inv_n;
    float var = q * inv_n - mu * mu;
    float sc  = gamma[tid] * rsqrtf(var + BN_EPS);
    lsc[tid] = sc;
    lsh[tid] = beta[tid] - mu * sc;
  }
  __syncthreads();

  const int lane = tid & 63;
  const int c0   = __builtin_amdgcn_readfirstlane((tid >> 6) * 32);
  const int lr   = lane & 15;
  const int lg   = lane >> 4;
  const int row0 = blockIdx.x * 32;

  const ushort* __restrict__ arow = h + (size_t)(row0 + lr) * DIM + lg * 8;
  const ushort* __restrict__ brow = Wt2 + (size_t)(c0 + lr) * DIM + lg * 8;

  f32x4 acc00 = {0, 0, 0, 0}, acc01 = {0, 0, 0, 0}, acc10 = {0, 0, 0, 0}, acc11 = {0, 0, 0, 0};

#pragma unroll
  for (int ks = 0; ks < 4; ++ks) {
    const int ch0 = lg * 8 + ks * 32;
    float sc[8], sh[8];
    *(float4*)(sc)     = *(const float4*)&lsc[ch0];
    *(float4*)(sc + 4) = *(const float4*)&lsc[ch0 + 4];
    *(float4*)(sh)     = *(const float4*)&lsh[ch0];
    *(float4*)(sh + 4) = *(const float4*)&lsh[ch0 + 4];
    bf16x8 a0 = bnrelu8(*(const bf16x8*)(arow + ks * 32), sc, sh);
    bf16x8 a1 = bnrelu8(*(const bf16x8*)(arow + 16 * DIM + ks * 32), sc, sh);
    bf16x8 b0 = *(const bf16x8*)(brow + ks * 32);
    bf16x8 b1 = *(const bf16x8*)(brow + 16 * DIM + ks * 32);
    acc00 = __builtin_amdgcn_mfma_f32_16x16x32_bf16(a0, b0, acc00, 0, 0, 0);
    acc01 = __builtin_amdgcn_mfma_f32_16x16x32_bf16(a0, b1, acc01, 0, 0, 0);
    acc10 = __builtin_amdgcn_mfma_f32_16x16x32_bf16(a1, b0, acc10, 0, 0, 0);
    acc11 = __builtin_amdgcn_mfma_f32_16x16x32_bf16(a1, b1, acc11, 0, 0, 0);
  }

  const float bia0 = b2[c0 + lr];
  const float bia1 = b2[c0 + 16 + lr];
  f32x4 accs[2][2] = {{acc00, acc01}, {acc10, acc11}};
#pragma unroll
  for (int rf = 0; rf < 2; ++rf) {
#pragma unroll
    for (int cf = 0; cf < 2; ++cf) {
      const int colidx = c0 + cf * 16 + lr;
      const float bb = cf ? bia1 : bia0;
#pragma unroll
      for (int rg = 0; rg < 4; ++rg) {
        float v = fmaxf(accs[rf][cf][rg] + bb, 0.f);
        const int row = row0 + rf * 16 + lg * 4 + rg;
        if (F32OUT) {
          outf[(size_t)row * DIM + colidx] = v;
        } else {
          float vp = __shfl_xor(v, 1);  // partner channel (lr^1)
          if (!(lr & 1)) {
            unsigned pk = __builtin_amdgcn_cvt_pk_fp8_f32(v, vp, 0, false);
            *(ushort*)(xf8 + (size_t)row * DIM + colidx) = (ushort)pk;
          }
        }
      }
    }
  }
}

// ---------------- segment pooling over sorted batch -------------------------------

__global__ __launch_bounds__(256) void pool_kernel(const float* __restrict__ x1,
                                                   const int* __restrict__ batch,
                                                   float* __restrict__ pooled) {
  const int grp  = (blockIdx.x * blockDim.x + threadIdx.x) >> 5;
  const int lane = threadIdx.x & 31;
  const int node0 = grp * 64;
  if (node0 >= N) return;
  const int end = (node0 + 64 < N) ? (node0 + 64) : N;
  float4 acc = {0, 0, 0, 0};
  int cur = batch[node0];
  for (int n = node0; n < end; ++n) {
    int b = batch[n];
    if (b != cur) {
      atomAddF(&pooled[(size_t)cur * DIM + lane * 4 + 0], acc.x);
      atomAddF(&pooled[(size_t)cur * DIM + lane * 4 + 1], acc.y);
      atomAddF(&pooled[(size_t)cur * DIM + lane * 4 + 2], acc.z);
      atomAddF(&pooled[(size_t)cur * DIM + lane * 4 + 3], acc.w);
      acc = {0, 0, 0, 0};
      cur = b;
    }
    float4 v = ((const float4*)x1)[(size_t)n * 32 + lane];
    acc.x += v.x; acc.y += v.y; acc.z += v.z; acc.w += v.w;
  }
  atomAddF(&pooled[(size_t)cur * DIM + lane * 4 + 0], acc.x);
  atomAddF(&pooled[(size_t)cur * DIM + lane * 4 + 1], acc.y);
  atomAddF(&pooled[(size_t)cur * DIM + lane * 4 + 2], acc.z);
  atomAddF(&pooled[(size_t)cur * DIM + lane * 4 + 3], acc.w);
}

// ---------------- final MLP + log_softmax -----------------------------------------

__global__ __launch_bounds__(128) void mlp_kernel(const float* __restrict__ pooled,
                                                  const float* __restrict__ W1,
                                                  const float* __restrict__ b1,
                                                  const float* __restrict__ W2,
                                                  const float* __restrict__ b2,
                                                  float* __restrict__ out) {
  const int gidx = blockIdx.x;
  const int t    = threadIdx.x;
  __shared__ float p[DIM], a1[DIM];
  p[t] = pooled[(size_t)gidx * DIM + t];
  __syncthreads();
  float acc = b1[t];
  for (int k = 0; k < DIM; ++k) acc = fmaf(p[k], W1[(size_t)k * DIM + t], acc);
  a1[t] = fmaxf(acc, 0.f);
  __syncthreads();
  if (t < OUTC) {
    float o = b2[t];
    for (int k = 0; k < DIM; ++k) o = fmaf(a1[k], W2[(size_t)k * OUTC + t], o);
    float m = o;
    for (int s = 8; s >= 1; s >>= 1) m = fmaxf(m, __shfl_xor(m, s, 16));
    float e = __expf(o - m);
    float se = e;
    for (int s = 8; s >= 1; s >>= 1) se += __shfl_xor(se, s, 16);
    out[(size_t)gidx * OUTC + t] = o - m - __logf(se);
  }
}

}  // namespace

extern "C" void kernel_launch(void* const* d_in, const int* in_sizes, int n_in,
                              void* d_out, int out_size, void* d_ws, size_t ws_size,
                              hipStream_t stream) {
  const float* x     = (const float*)d_in[0];
  const int*   ei    = (const int*)d_in[1];
  const int*   batch = (const int*)d_in[2];
  const float* W1_0  = (const float*)d_in[4];
  const float* b1_0  = (const float*)d_in[5];
  const float* g_0   = (const float*)d_in[6];
  const float* bt_0  = (const float*)d_in[7];
  const float* W2_0  = (const float*)d_in[8];
  const float* b2_0  = (const float*)d_in[9];
  const float* W1s   = (const float*)d_in[10];
  const float* b1s   = (const float*)d_in[11];
  const float* gs    = (const float*)d_in[12];
  const float* bts   = (const float*)d_in[13];
  const float* W2s   = (const float*)d_in[14];
  const float* b2s   = (const float*)d_in[15];
  const float* lin1W = (const float*)d_in[16];
  const float* lin1b = (const float*)d_in[17];
  const float* lin2W = (const float*)d_in[18];
  const float* lin2b = (const float*)d_in[19];

  float* out_ls = (float*)d_out;              // [256,16]
  float* x1_out = (float*)d_out + NG * OUTC;  // [40000,128] f32

  char* w = (char*)d_ws;
  auto alloc = [&](size_t bytes) -> void* {
    void* p = (void*)w;
    w += (bytes + 255) & ~(size_t)255;
    return p;
  };
  // zero region: deg+counter | statsAll+pooled  (contiguous -> one memset)
  int*    deg      = (int*)alloc((size_t)(N + 64) * 4);          // 160256 B (256-aligned)
  int*    counter  = deg + N;
  float*  statsAll = (float*)alloc((size_t)(5 * 8 * 2 * DIM + NG * DIM) * 4);
  float*  pooled   = statsAll + 5 * 8 * 2 * DIM;
  const size_t zero_bytes = (size_t)(N + 64) * 4 + (size_t)(5 * 8 * 2 * DIM + NG * DIM) * 4;

  int*    start  = (int*)alloc((size_t)N * 4);
  int*    cursor = (int*)alloc((size_t)N * 4);
  int*    col    = (int*)alloc((size_t)E * 4);
  unsigned char* xf8 = (unsigned char*)alloc((size_t)N * DIM);   // fp8 activations
  ushort* act    = (ushort*)alloc((size_t)N * DIM * 2);          // h (bf16)
  ushort* Wt     = (ushort*)alloc((size_t)10 * DIM * DIM * 2);

  const int* src = ei;
  const int* dst = ei + E;

  hipMemsetAsync(deg, 0, zero_bytes, stream);

  // prep: cvt x->fp8 | hist | weight transpose  (one kernel)
  prep_kernel<<<CVT_B + HIST_B + TRANS_B, 256, 0, stream>>>(x, xf8, dst, deg,
                                                            W1_0, W2_0, W1s, W2s, Wt);
  alloc_kernel<<<(N + 255) / 256, 256, 0, stream>>>(deg, counter, start, cursor);
  fill_kernel<<<E / 256, 256, 0, stream>>>(src, dst, cursor, col);

  // 5 GIN layers
  for (int l = 0; l < 5; ++l) {
    const float* b1 = (l == 0) ? b1_0 : b1s + (size_t)(l - 1) * DIM;
    const float* gg = (l == 0) ? g_0  : gs  + (size_t)(l - 1) * DIM;
    const float* bb = (l == 0) ? bt_0 : bts + (size_t)(l - 1) * DIM;
    const float* b2 = (l == 0) ? b2_0 : b2s + (size_t)(l - 1) * DIM;
    const ushort* Wt1 = Wt + (size_t)(2 * l) * DIM * DIM;
    const ushort* Wt2 = Wt + (size_t)(2 * l + 1) * DIM * DIM;
    float* stats8 = statsAll + (size_t)l * 8 * 2 * DIM;

    gin1_fused<<<N / 64, 512, 0, stream>>>(xf8, start, deg, col, Wt1, b1, act, stats8);
    if (l == 4)
      gin2_fused<1><<<N / 32, 256, 0, stream>>>(act, stats8, gg, bb, Wt2, b2, nullptr, x1_out);
    else
      gin2_fused<0><<<N / 32, 256, 0, stream>>>(act, stats8, gg, bb, Wt2, b2, xf8, nullptr);
  }

  // pooling + MLP head
  {
    int groups = (N + 63) / 64;
    int blocks = (groups * 32 + 255) / 256;
    pool_kernel<<<blocks, 256, 0, stream>>>(x1_out, batch, pooled);
  }
  mlp_kernel<<<NG, 128, 0, stream>>>(pooled, lin1W, lin1b, lin2W, lin2b, out_ls);
}

// Round 6
// 314.781 us; speedup vs baseline: 5.8769x; 1.0053x over previous
//
#include <hip/hip_runtime.h>

namespace {

constexpr int N    = 40000;
constexpr int E    = 640000;
constexpr int DIM  = 128;
constexpr int NG   = 256;
constexpr int OUTC = 16;
constexpr float BN_EPS = 1e-5f;
constexpr size_t SLAB = (size_t)N * 64;  // bytes per channel-slab (N x 64 fp8)

typedef __attribute__((ext_vector_type(8))) short bf16x8;
typedef __attribute__((ext_vector_type(4))) float f32x4;
typedef __attribute__((ext_vector_type(2))) float f32x2;

__device__ __forceinline__ void atomAddF(float* p, float v) {
  unsafeAtomicAdd(p, v);
}

// round-to-nearest-even f32 -> bf16 (as uint in low 16)
__device__ __forceinline__ unsigned b16r(float f) {
  unsigned u = __float_as_uint(f);
  return (u + 0x7fffu + ((u >> 16) & 1u)) >> 16;
}
__device__ __forceinline__ unsigned pack2(float a, float b) {
  return b16r(a) | (b16r(b) << 16);
}

// fp8 e4m3 (OCP) helpers — hardware cvt
__device__ __forceinline__ unsigned pk4_fp8(float4 v) {
  unsigned u = __builtin_amdgcn_cvt_pk_fp8_f32(v.x, v.y, 0, false);
  u = __builtin_amdgcn_cvt_pk_fp8_f32(v.z, v.w, u, true);
  return u;
}
__device__ __forceinline__ void addfp8x4(float* a, unsigned u) {
  f32x2 lo = __builtin_amdgcn_cvt_pk_f32_fp8(u, false);
  f32x2 hi = __builtin_amdgcn_cvt_pk_f32_fp8(u, true);
  a[0] += lo[0]; a[1] += lo[1]; a[2] += hi[0]; a[3] += hi[1];
}
__device__ __forceinline__ void add16(float* a, const uint4 v) {
  addfp8x4(a, v.x); addfp8x4(a + 4, v.y); addfp8x4(a + 8, v.z); addfp8x4(a + 12, v.w);
}

// rot4 swizzle: bijective in [0,16), spreads low-3 chunk bits across 16 rows
__device__ __forceinline__ int rot4(int r) {
  return ((r << 1) | ((r >> 3) & 1)) & 15;
}

// BN+relu on 8 packed bf16 values, repacked to bf16x8
__device__ __forceinline__ bf16x8 bnrelu8(bf16x8 a, const float* sc, const float* sh) {
  union { bf16x8 v; unsigned u[4]; } in, out;
  in.v = a;
#pragma unroll
  for (int p = 0; p < 4; ++p) {
    float lo = __uint_as_float(in.u[p] << 16);
    float hi = __uint_as_float(in.u[p] & 0xffff0000u);
    lo = fmaxf(fmaf(lo, sc[2 * p], sh[2 * p]), 0.f);
    hi = fmaxf(fmaf(hi, sc[2 * p + 1], sh[2 * p + 1]), 0.f);
    out.u[p] = pack2(lo, hi);
  }
  return out.v;
}

// ---------------- prep: cvt x->fp8 slabs  |  degree histogram  |  W transpose ----
constexpr int CVT_B   = (N * DIM / 4) / 256;  // 5000
constexpr int HIST_B  = E / 256;              // 2500
constexpr int TRANS_B = 10 * DIM / 4;         // 320

__global__ __launch_bounds__(256) void prep_kernel(const float* __restrict__ x,
                                                   unsigned char* __restrict__ xf8,
                                                   const int* __restrict__ dst,
                                                   int* __restrict__ deg,
                                                   const float* __restrict__ W1_0,
                                                   const float* __restrict__ W2_0,
                                                   const float* __restrict__ W1s,
                                                   const float* __restrict__ W2s,
                                                   ushort* __restrict__ Wt) {
  const int b = blockIdx.x;
  if (b < CVT_B) {
    const int i = b * 256 + threadIdx.x;      // one float4 = 4 consecutive channels
    float4 v = ((const float4*)x)[i];
    const int row = i >> 5;                   // node
    const int c0  = (i & 31) * 4;             // channel
    ((unsigned*)xf8)[(size_t)(c0 >> 6) * (N * 16) + (size_t)row * 16 + ((c0 & 63) >> 2)] =
        pk4_fp8(v);
  } else if (b < CVT_B + HIST_B) {
    const int e = (b - CVT_B) * 256 + threadIdx.x;
    atomicAdd(&deg[dst[e]], 1);
  } else {
    const int ob   = (b - CVT_B - HIST_B) * 4 + (threadIdx.x >> 6);  // 0..1279
    const int lane = threadIdx.x & 63;
    const int m = ob >> 7;   // matrix 0..9
    const int c = ob & 127;  // out-channel
    const int l = m >> 1;
    const float* W;
    if (l == 0) W = (m & 1) ? W2_0 : W1_0;
    else        W = ((m & 1) ? W2s : W1s) + (size_t)(l - 1) * DIM * DIM;
    const int k = lane * 2;
    float f0 = W[(size_t)k * DIM + c];
    float f1 = W[(size_t)(k + 1) * DIM + c];
    ((unsigned*)Wt)[((size_t)m * DIM + c) * 64 + lane] = pack2(f0, f1);
  }
}

// ---------------- CSR build (order-free segments) ----------------

__global__ __launch_bounds__(256) void alloc_kernel(const int* __restrict__ deg,
                                                    int* __restrict__ counter,
                                                    int* __restrict__ start,
                                                    int* __restrict__ cursor) {
  const int i    = blockIdx.x * blockDim.x + threadIdx.x;
  const int lane = threadIdx.x & 63;
  int d = (i < N) ? deg[i] : 0;
  int incl = d;
#pragma unroll
  for (int o = 1; o < 64; o <<= 1) {
    int v = __shfl_up(incl, o, 64);
    if (lane >= o) incl += v;
  }
  int base = 0;
  if (lane == 63) base = atomicAdd(counter, incl);
  base = __shfl(base, 63, 64);
  int s0 = base + incl - d;
  if (i < N) { start[i] = s0; cursor[i] = s0; }
}

__global__ void fill_kernel(const int* __restrict__ src, const int* __restrict__ dst,
                            int* __restrict__ cursor, int* __restrict__ col) {
  int e = blockIdx.x * blockDim.x + threadIdx.x;
  if (e < E) {
    int p = atomicAdd(&cursor[dst[e]], 1);
    col[p] = src[e];
  }
}

// ---------------- fused GIN part 1: two-slab fp8 gather -> LDS -> MFMA(W1) -------
// 256 thr; 64 nodes/block; gather = 4 lanes/node x 16B over 2 slab passes
// (resident set per pass = 2.56 MB -> per-XCD L2). GEMM: 4 waves, 32 rows x 64 cols.

__global__ __launch_bounds__(256) void gin1_fused(const unsigned char* __restrict__ xf8,
                                                  const int* __restrict__ start,
                                                  const int* __restrict__ deg,
                                                  const int* __restrict__ col,
                                                  const ushort* __restrict__ Wt1,
                                                  const float* __restrict__ b1,
                                                  ushort* __restrict__ h,
                                                  float* __restrict__ stats8) {
  __shared__ uint4 tile4[64 * 16];  // 16 KB, rot4-swizzled 16B chunks
  const int tid   = threadIdx.x;
  const int node0 = blockIdx.x * 64;

  // ---- phase 1: gather (slab A, then slab B) ----
  {
    const int r = tid >> 2;   // 0..63 node-in-block
    const int l = tid & 3;    // 16B chunk within 64B slab row
    const int node = node0 + r;
    const int b = start[node], n = deg[node];
    const int sw = rot4(r);
#pragma unroll 1
    for (int s = 0; s < 2; ++s) {
      const uint4* __restrict__ x16 = (const uint4*)(xf8 + (size_t)s * SLAB);
      float a[16];
#pragma unroll
      for (int i = 0; i < 16; ++i) a[i] = 0.f;
      add16(a, x16[(size_t)node * 4 + l]);  // self
      int k = 0;
      for (; k + 4 <= n; k += 4) {
        int j0 = col[b + k], j1 = col[b + k + 1], j2 = col[b + k + 2], j3 = col[b + k + 3];
        uint4 v0 = x16[(size_t)j0 * 4 + l];
        uint4 v1 = x16[(size_t)j1 * 4 + l];
        uint4 v2 = x16[(size_t)j2 * 4 + l];
        uint4 v3 = x16[(size_t)j3 * 4 + l];
        add16(a, v0); add16(a, v1); add16(a, v2); add16(a, v3);
      }
      for (; k < n; ++k) add16(a, x16[(size_t)col[b + k] * 4 + l]);
      uint4 o0 = {pack2(a[0], a[1]), pack2(a[2], a[3]), pack2(a[4], a[5]), pack2(a[6], a[7])};
      uint4 o1 = {pack2(a[8], a[9]), pack2(a[10], a[11]), pack2(a[12], a[13]), pack2(a[14], a[15])};
      const int cb = s * 8 + 2 * l;
      tile4[r * 16 + (cb ^ sw)]       = o0;
      tile4[r * 16 + ((cb + 1) ^ sw)] = o1;
    }
  }
  __syncthreads();

  // ---- phase 2: GEMM ----
  const int w    = tid >> 6;
  const int lane = tid & 63;
  const int rh   = __builtin_amdgcn_readfirstlane(w >> 1);        // row group (32 rows)
  const int c0   = __builtin_amdgcn_readfirstlane((w & 1) * 64);  // col slice (64 cols)
  const int lr   = lane & 15;
  const int lg   = lane >> 4;

  const bf16x8* __restrict__ tb = (const bf16x8*)tile4;
  const int r0 = rh * 32 + lr, r1 = r0 + 16;
  const int sw0 = rot4(r0 & 15);  // == rot4(r1 & 15)

  const ushort* __restrict__ brow = Wt1 + (size_t)(c0 + lr) * DIM + lg * 8;

  f32x4 acc[2][4];
#pragma unroll
  for (int i = 0; i < 2; ++i)
#pragma unroll
    for (int j = 0; j < 4; ++j) acc[i][j] = {0, 0, 0, 0};

#pragma unroll
  for (int ks = 0; ks < 4; ++ks) {
    bf16x8 a0 = tb[r0 * 16 + ((lg + ks * 4) ^ sw0)];
    bf16x8 a1 = tb[r1 * 16 + ((lg + ks * 4) ^ sw0)];
#pragma unroll
    for (int cf = 0; cf < 4; ++cf) {
      bf16x8 bf = *(const bf16x8*)(brow + (size_t)cf * 16 * DIM + ks * 32);
      acc[0][cf] = __builtin_amdgcn_mfma_f32_16x16x32_bf16(a0, bf, acc[0][cf], 0, 0, 0);
      acc[1][cf] = __builtin_amdgcn_mfma_f32_16x16x32_bf16(a1, bf, acc[1][cf], 0, 0, 0);
    }
  }

  // ---- epilogue: bias, h write, BN stats ----
  float s[4] = {0, 0, 0, 0}, q[4] = {0, 0, 0, 0};
#pragma unroll
  for (int rf = 0; rf < 2; ++rf) {
#pragma unroll
    for (int cf = 0; cf < 4; ++cf) {
      const int colidx = c0 + cf * 16 + lr;
      const float bb = b1[colidx];
#pragma unroll
      for (int rg = 0; rg < 4; ++rg) {
        float v = acc[rf][cf][rg] + bb;
        const int row = node0 + rh * 32 + rf * 16 + lg * 4 + rg;
        h[(size_t)row * DIM + colidx] = (ushort)b16r(v);
        s[cf] += v; q[cf] = fmaf(v, v, q[cf]);
      }
    }
  }
#pragma unroll
  for (int cf = 0; cf < 4; ++cf) {
    float ss = s[cf], qq = q[cf];
    ss += __shfl_xor(ss, 16); ss += __shfl_xor(ss, 32);
    qq += __shfl_xor(qq, 16); qq += __shfl_xor(qq, 32);
    if (lg == 0) {
      float* st = stats8 + (blockIdx.x & 7) * 2 * DIM;
      atomAddF(&st[c0 + cf * 16 + lr], ss);
      atomAddF(&st[DIM + c0 + cf * 16 + lr], qq);
    }
  }
}

// ---------------- fused GIN part 2: BN(+relu) on A-load -> MFMA(W2) -> fp8/f32 ----

template <int F32OUT>
__global__ __launch_bounds__(256) void gin2_fused(const ushort* __restrict__ h,
                                                  const float* __restrict__ stats8,
                                                  const float* __restrict__ gamma,
                                                  const float* __restrict__ beta,
                                                  const ushort* __restrict__ Wt2,
                                                  const float* __restrict__ b2,
                                                  unsigned char* __restrict__ xf8,
                                                  float* __restrict__ outf) {
  __shared__ float lsc[DIM], lsh[DIM];
  const int tid = threadIdx.x;
  if (tid < DIM) {
    float s = 0.f, q = 0.f;
#pragma unroll
    for (int p = 0; p < 8; ++p) {
      s += stats8[p * 2 * DIM + tid];
      q += stats8[p * 2 * DIM + DIM + tid];
    }
    const float inv_n = 1.0f / N;
    float mu  = s * inv_n;
    float var = q * inv_n - mu * mu;
    float sc  = gamma[tid] * rsqrtf(var + BN_EPS);
    lsc[tid] = sc;
    lsh[tid] = beta[tid] - mu * sc;
  }
  __syncthreads();

  const int lane = tid & 63;
  const int c0   = __builtin_amdgcn_readfirstlane((tid >> 6) * 32);
  const int lr   = lane & 15;
  const int lg   = lane >> 4;
  const int row0 = blockIdx.x * 32;

  const ushort* __restrict__ arow = h + (size_t)(row0 + lr) * DIM + lg * 8;
  const ushort* __restrict__ brow = Wt2 + (size_t)(c0 + lr) * DIM + lg * 8;

  f32x4 acc00 = {0, 0, 0, 0}, acc01 = {0, 0, 0, 0}, acc10 = {0, 0, 0, 0}, acc11 = {0, 0, 0, 0};

#pragma unroll
  for (int ks = 0; ks < 4; ++ks) {
    const int ch0 = lg * 8 + ks * 32;
    float sc[8], sh[8];
    *(float4*)(sc)     = *(const float4*)&lsc[ch0];
    *(float4*)(sc + 4) = *(const float4*)&lsc[ch0 + 4];
    *(float4*)(sh)     = *(const float4*)&lsh[ch0];
    *(float4*)(sh + 4) = *(const float4*)&lsh[ch0 + 4];
    bf16x8 a0 = bnrelu8(*(const bf16x8*)(arow + ks * 32), sc, sh);
    bf16x8 a1 = bnrelu8(*(const bf16x8*)(arow + 16 * DIM + ks * 32), sc, sh);
    bf16x8 b0 = *(const bf16x8*)(brow + ks * 32);
    bf16x8 b1 = *(const bf16x8*)(brow + 16 * DIM + ks * 32);
    acc00 = __builtin_amdgcn_mfma_f32_16x16x32_bf16(a0, b0, acc00, 0, 0, 0);
    acc01 = __builtin_amdgcn_mfma_f32_16x16x32_bf16(a0, b1, acc01, 0, 0, 0);
    acc10 = __builtin_amdgcn_mfma_f32_16x16x32_bf16(a1, b0, acc10, 0, 0, 0);
    acc11 = __builtin_amdgcn_mfma_f32_16x16x32_bf16(a1, b1, acc11, 0, 0, 0);
  }

  const float bia0 = b2[c0 + lr];
  const float bia1 = b2[c0 + 16 + lr];
  f32x4 accs[2][2] = {{acc00, acc01}, {acc10, acc11}};
#pragma unroll
  for (int rf = 0; rf < 2; ++rf) {
#pragma unroll
    for (int cf = 0; cf < 2; ++cf) {
      const int colidx = c0 + cf * 16 + lr;
      const float bb = cf ? bia1 : bia0;
#pragma unroll
      for (int rg = 0; rg < 4; ++rg) {
        float v = fmaxf(accs[rf][cf][rg] + bb, 0.f);
        const int row = row0 + rf * 16 + lg * 4 + rg;
        if (F32OUT) {
          outf[(size_t)row * DIM + colidx] = v;
        } else {
          float vp = __shfl_xor(v, 1);  // partner channel (lr^1)
          if (!(lr & 1)) {
            unsigned pk = __builtin_amdgcn_cvt_pk_fp8_f32(v, vp, 0, false);
            unsigned char* dp = xf8 + (size_t)(colidx >> 6) * SLAB +
                                (size_t)row * 64 + (colidx & 63);
            *(ushort*)dp = (ushort)pk;
          }
        }
      }
    }
  }
}

// ---------------- segment pooling over sorted batch -------------------------------

__global__ __launch_bounds__(256) void pool_kernel(const float* __restrict__ x1,
                                                   const int* __restrict__ batch,
                                                   float* __restrict__ pooled) {
  const int grp  = (blockIdx.x * blockDim.x + threadIdx.x) >> 5;
  const int lane = threadIdx.x & 31;
  const int node0 = grp * 64;
  if (node0 >= N) return;
  const int end = (node0 + 64 < N) ? (node0 + 64) : N;
  float4 acc = {0, 0, 0, 0};
  int cur = batch[node0];
  for (int n = node0; n < end; ++n) {
    int b = batch[n];
    if (b != cur) {
      atomAddF(&pooled[(size_t)cur * DIM + lane * 4 + 0], acc.x);
      atomAddF(&pooled[(size_t)cur * DIM + lane * 4 + 1], acc.y);
      atomAddF(&pooled[(size_t)cur * DIM + lane * 4 + 2], acc.z);
      atomAddF(&pooled[(size_t)cur * DIM + lane * 4 + 3], acc.w);
      acc = {0, 0, 0, 0};
      cur = b;
    }
    float4 v = ((const float4*)x1)[(size_t)n * 32 + lane];
    acc.x += v.x; acc.y += v.y; acc.z += v.z; acc.w += v.w;
  }
  atomAddF(&pooled[(size_t)cur * DIM + lane * 4 + 0], acc.x);
  atomAddF(&pooled[(size_t)cur * DIM + lane * 4 + 1], acc.y);
  atomAddF(&pooled[(size_t)cur * DIM + lane * 4 + 2], acc.z);
  atomAddF(&pooled[(size_t)cur * DIM + lane * 4 + 3], acc.w);
}

// ---------------- final MLP + log_softmax -----------------------------------------

__global__ __launch_bounds__(128) void mlp_kernel(const float* __restrict__ pooled,
                                                  const float* __restrict__ W1,
                                                  const float* __restrict__ b1,
                                                  const float* __restrict__ W2,
                                                  const float* __restrict__ b2,
                                                  float* __restrict__ out) {
  const int gidx = blockIdx.x;
  const int t    = threadIdx.x;
  __shared__ float p[DIM], a1[DIM];
  p[t] = pooled[(size_t)gidx * DIM + t];
  __syncthreads();
  float acc = b1[t];
  for (int k = 0; k < DIM; ++k) acc = fmaf(p[k], W1[(size_t)k * DIM + t], acc);
  a1[t] = fmaxf(acc, 0.f);
  __syncthreads();
  if (t < OUTC) {
    float o = b2[t];
    for (int k = 0; k < DIM; ++k) o = fmaf(a1[k], W2[(size_t)k * OUTC + t], o);
    float m = o;
    for (int s = 8; s >= 1; s >>= 1) m = fmaxf(m, __shfl_xor(m, s, 16));
    float e = __expf(o - m);
    float se = e;
    for (int s = 8; s >= 1; s >>= 1) se += __shfl_xor(se, s, 16);
    out[(size_t)gidx * OUTC + t] = o - m - __logf(se);
  }
}

}  // namespace

extern "C" void kernel_launch(void* const* d_in, const int* in_sizes, int n_in,
                              void* d_out, int out_size, void* d_ws, size_t ws_size,
                              hipStream_t stream) {
  const float* x     = (const float*)d_in[0];
  const int*   ei    = (const int*)d_in[1];
  const int*   batch = (const int*)d_in[2];
  const float* W1_0  = (const float*)d_in[4];
  const float* b1_0  = (const float*)d_in[5];
  const float* g_0   = (const float*)d_in[6];
  const float* bt_0  = (const float*)d_in[7];
  const float* W2_0  = (const float*)d_in[8];
  const float* b2_0  = (const float*)d_in[9];
  const float* W1s   = (const float*)d_in[10];
  const float* b1s   = (const float*)d_in[11];
  const float* gs    = (const float*)d_in[12];
  const float* bts   = (const float*)d_in[13];
  const float* W2s   = (const float*)d_in[14];
  const float* b2s   = (const float*)d_in[15];
  const float* lin1W = (const float*)d_in[16];
  const float* lin1b = (const float*)d_in[17];
  const float* lin2W = (const float*)d_in[18];
  const float* lin2b = (const float*)d_in[19];

  float* out_ls = (float*)d_out;              // [256,16]
  float* x1_out = (float*)d_out + NG * OUTC;  // [40000,128] f32

  char* w = (char*)d_ws;
  auto alloc = [&](size_t bytes) -> void* {
    void* p = (void*)w;
    w += (bytes + 255) & ~(size_t)255;
    return p;
  };
  // zero region: deg+counter | statsAll+pooled  (contiguous -> one memset)
  int*    deg      = (int*)alloc((size_t)(N + 64) * 4);
  int*    counter  = deg + N;
  float*  statsAll = (float*)alloc((size_t)(5 * 8 * 2 * DIM + NG * DIM) * 4);
  float*  pooled   = statsAll + 5 * 8 * 2 * DIM;
  const size_t zero_bytes = (size_t)(N + 64) * 4 + (size_t)(5 * 8 * 2 * DIM + NG * DIM) * 4;

  int*    start  = (int*)alloc((size_t)N * 4);
  int*    cursor = (int*)alloc((size_t)N * 4);
  int*    col    = (int*)alloc((size_t)E * 4);
  unsigned char* xf8 = (unsigned char*)alloc(2 * SLAB);   // fp8 activations, 2 slabs
  ushort* act    = (ushort*)alloc((size_t)N * DIM * 2);   // h (bf16)
  ushort* Wt     = (ushort*)alloc((size_t)10 * DIM * DIM * 2);

  const int* src = ei;
  const int* dst = ei + E;

  hipMemsetAsync(deg, 0, zero_bytes, stream);

  // prep: cvt x->fp8 slabs | hist | weight transpose  (one kernel)
  prep_kernel<<<CVT_B + HIST_B + TRANS_B, 256, 0, stream>>>(x, xf8, dst, deg,
                                                            W1_0, W2_0, W1s, W2s, Wt);
  alloc_kernel<<<(N + 255) / 256, 256, 0, stream>>>(deg, counter, start, cursor);
  fill_kernel<<<E / 256, 256, 0, stream>>>(src, dst, cursor, col);

  // 5 GIN layers
  for (int l = 0; l < 5; ++l) {
    const float* b1 = (l == 0) ? b1_0 : b1s + (size_t)(l - 1) * DIM;
    const float* gg = (l == 0) ? g_0  : gs  + (size_t)(l - 1) * DIM;
    const float* bb = (l == 0) ? bt_0 : bts + (size_t)(l - 1) * DIM;
    const float* b2 = (l == 0) ? b2_0 : b2s + (size_t)(l - 1) * DIM;
    const ushort* Wt1 = Wt + (size_t)(2 * l) * DIM * DIM;
    const ushort* Wt2 = Wt + (size_t)(2 * l + 1) * DIM * DIM;
    float* stats8 = statsAll + (size_t)l * 8 * 2 * DIM;

    gin1_fused<<<N / 64, 256, 0, stream>>>(xf8, start, deg, col, Wt1, b1, act, stats8);
    if (l == 4)
      gin2_fused<1><<<N / 32, 256, 0, stream>>>(act, stats8, gg, bb, Wt2, b2, nullptr, x1_out);
    else
      gin2_fused<0><<<N / 32, 256, 0, stream>>>(act, stats8, gg, bb, Wt2, b2, xf8, nullptr);
  }

  // pooling + MLP head
  {
    int groups = (N + 63) / 64;
    int blocks = (groups * 32 + 255) / 256;
    pool_kernel<<<blocks, 256, 0, stream>>>(x1_out, batch, pooled);
  }
  mlp_kernel<<<NG, 128, 0, stream>>>(pooled, lin1W, lin1b, lin2W, lin2b, out_ls);
}